// Round 1
// baseline (258.124 us; speedup 1.0000x reference)
//
#include <hip/hip_runtime.h>
#include <stdint.h>
#include <math.h>

// Problem: B=2, T=2048, H=16, hd=64, D=1024, 3D=3072
// I/O dtype: float32 (per reference). Internal MFMA pipeline: bf16.
// d_out: [out (2,2048,1024)] ++ [new_cache (2,2,2048,16,64)], fp32
// d_in: x, Wqkv, bqkv, Wout, bout (fp32), offset (int32)

typedef __bf16 bf16_t;
typedef bf16_t bf16x8 __attribute__((ext_vector_type(8)));
typedef float f32x4 __attribute__((ext_vector_type(4)));
typedef unsigned short ushort8_t __attribute__((ext_vector_type(8)));

__device__ __forceinline__ unsigned short f2bf(float f) {
    union { float f; unsigned int i; } v; v.f = f;
    unsigned int r = v.i + 0x7fffu + ((v.i >> 16) & 1u);
    return (unsigned short)(r >> 16);
}
__device__ __forceinline__ bf16x8 ld8(const unsigned short* p) {
    return *(const bf16x8*)p;
}
__device__ __forceinline__ void gload_lds16(const unsigned short* g, unsigned short* l) {
    __builtin_amdgcn_global_load_lds(
        (__attribute__((address_space(1))) void*)(g),
        (__attribute__((address_space(3))) void*)(l),
        16, 0, 0);
}

// ---------------- fp32 -> bf16 bulk convert (8 elems/thread) ----------------
__global__ void k_cvt(const float* __restrict__ in, unsigned short* __restrict__ out) {
    const int i = (blockIdx.x * 256 + threadIdx.x) * 8;
    float4 a = *(const float4*)&in[i];
    float4 b = *(const float4*)&in[i + 4];
    ushort8_t v;
    v[0] = f2bf(a.x); v[1] = f2bf(a.y); v[2] = f2bf(a.z); v[3] = f2bf(a.w);
    v[4] = f2bf(b.x); v[5] = f2bf(b.y); v[6] = f2bf(b.z); v[7] = f2bf(b.w);
    *(ushort8_t*)&out[i] = v;
}

// ---------------- RoPE cos/sin table: tab[t][i][2], t<2048, i<32 ----------------
__global__ void k_ropetab(float* __restrict__ tab, const int* __restrict__ offp) {
    int idx = blockIdx.x * blockDim.x + threadIdx.x;   // 65536 threads
    int t = idx >> 5, i = idx & 31;
    float off = (float)(*offp);
    float inv = powf(10000.0f, -(float)(2 * i) / 64.0f);
    float ang = ((float)t + off) * inv;
    float s, c;
    sincosf(ang, &s, &c);
    tab[idx * 2]     = c;
    tab[idx * 2 + 1] = s;
}

// ------- 64x64 tile transpose + downconvert: in fp32 [bz][R][C] -> out bf16 [bz][C][R] -------
__global__ void k_transposeF2B(const float* __restrict__ in,
                               unsigned short* __restrict__ out, int R, int C) {
    __shared__ __align__(16) float tile[64 * 68];
    const int bz = blockIdx.z;
    const size_t base = (size_t)bz * R * C;
    const int tR = blockIdx.y * 64, tC = blockIdx.x * 64;
    const int tid = threadIdx.x;
#pragma unroll
    for (int it = 0; it < 4; ++it) {
        int flat = (it * 256 + tid) * 4;
        int r = flat >> 6, c = flat & 63;
        *(float4*)&tile[r * 68 + c] =
            *(const float4*)&in[base + (size_t)(tR + r) * C + tC + c];
    }
    __syncthreads();
#pragma unroll
    for (int it = 0; it < 2; ++it) {
        int flat = (it * 256 + tid) * 8;
        int rr = flat >> 6, cc = flat & 63;
        ushort8_t v;
#pragma unroll
        for (int j = 0; j < 8; ++j) v[j] = f2bf(tile[(cc + j) * 68 + rr]);
        *(ushort8_t*)&out[base + (size_t)(tC + rr) * R + tR + cc] = v;
    }
}

// ---------------- batched bf16 64x64 tile transpose: in[bz][R][C] -> out[bz][C][R] ----------------
__global__ void k_transpose64(const unsigned short* __restrict__ in,
                              unsigned short* __restrict__ out, int R, int C) {
    __shared__ __align__(16) unsigned short tile[64 * 72];
    const int bz = blockIdx.z;
    const size_t base = (size_t)bz * R * C;
    const int tR = blockIdx.y * 64, tC = blockIdx.x * 64;
    const int tid = threadIdx.x;
#pragma unroll
    for (int it = 0; it < 2; ++it) {
        int flat = (it * 256 + tid) * 8;
        int r = flat >> 6, c = flat & 63;
        *(ushort8_t*)&tile[r * 72 + c] =
            *(const ushort8_t*)&in[base + (size_t)(tR + r) * C + tC + c];
    }
    __syncthreads();
#pragma unroll
    for (int it = 0; it < 2; ++it) {
        int flat = (it * 256 + tid) * 8;
        int rr = flat >> 6, cc = flat & 63;
        ushort8_t v;
#pragma unroll
        for (int j = 0; j < 8; ++j) v[j] = tile[(cc + j) * 72 + rr];
        *(ushort8_t*)&out[base + (size_t)(tC + rr) * R + tR + cc] = v;
    }
}

// ================= 256x256 MFMA GEMM, K=1024, BK=64, 8-wave, 8-phase schedule =================
// T1: bijective XCD swizzle (grid % 8 == 0).
// T2: LDS XOR swizzle; gload_lds writes LINEAR dest, global SOURCE pre-permuted
//     (involution), ds_read applies the same XOR -> 2-way residual conflict (free).
// T3/T4: ring of 4 half-tiles per matrix (half = 256 rows x 32 k = 16 KB). One half
//     staged per phase, consumed 6 phases later; s_waitcnt vmcnt(6) per phase keeps
//     3 half-tiles in flight ACROSS raw s_barriers (never drains to 0 in the loop).
//     WAR: each ring slot is re-staged >=1 barrier after its last reader's lgkmcnt(0).
// T5: setprio(1) around each 16-MFMA cluster.
// Waves: 2(M) x 4(N); per-wave C = 128x64 = acc[8][4] f32x4. LDS 128 KiB -> 1 block/CU.
// EPI 0: out-proj  (bias + fp32 store)    EPI 1: qkv (bias + rope + scatter + cache)
template <int EPI>
__global__ __launch_bounds__(512, 2) void k_gemm(
    const unsigned short* __restrict__ A,
    const unsigned short* __restrict__ Bt,
    const float* __restrict__ bias,
    const float* __restrict__ tab,
    unsigned short* __restrict__ oq,
    unsigned short* __restrict__ ok,
    unsigned short* __restrict__ ov,
    float* __restrict__ cache,
    float* __restrict__ outp)
{
    constexpr int K = 1024;
    constexpr int NT = 16;                       // K / 64 K-tiles
    __shared__ __align__(16) unsigned short lds[65536];   // 128 KiB
    unsigned short* lA = lds;                    // 4 slots x 8192 ushorts (16 KB)
    unsigned short* lB = lds + 32768;

    const int tid  = threadIdx.x;
    const int lane = tid & 63, w = tid >> 6;
    const int wr = w >> 2, wc = w & 3;           // 2 x 4 wave grid
    const int lrow = lane & 15, quad = lane >> 4;

    // --- T1: XCD-aware bijective swizzle (nwg % 8 == 0 for both launches) ---
    const int gx  = gridDim.x;
    const int nwg = gx * gridDim.y;
    const int bid = blockIdx.y * gx + blockIdx.x;
    const int sw  = (bid & 7) * (nwg >> 3) + (bid >> 3);
    const int blockM = (sw / gx) * 256;
    const int blockN = (sw % gx) * 256;

    // --- staging: linear LDS dest, pre-swizzled global source (T2, rule #21) ---
    // LDS byte x in a half: ldsrow = x>>7; element (row,col) with
    //   row = 2*ldsrow + bit, col = f(x) where inner 128B is XOR'd by (ldsrow&7)<<4.
    const int q8    = (lane & 7) ^ (lane >> 3);
    const int srow0 = ((w * 16 + (lane >> 3)) << 1) + ((q8 >> 2) & 1);
    const int scol  = (q8 & 3) * 8;
    const unsigned short* srcA = A  + (size_t)(blockM + srow0) * K + scol;
    const unsigned short* srcB = Bt + (size_t)(blockN + srow0) * K + scol;
    unsigned short* dA = lA + w * 1024;          // + slot*8192 at use
    unsigned short* dB = lB + w * 1024;

    // --- frag reads: same XOR on the read side -> 2-way bank conflict (free) ---
    const int rp   = lrow >> 1;
    const int swzu = ((((lane & 1) << 6) | (quad << 4)) ^ (rp << 4)) >> 1;

    f32x4 acc[8][4];
#pragma unroll
    for (int m = 0; m < 8; ++m)
#pragma unroll
        for (int n = 0; n < 4; ++n) acc[m][n] = (f32x4){0.f, 0.f, 0.f, 0.f};

#define STAGE_A(T, KH) do { \
        const unsigned short* s_ = srcA + (T) * 64 + (KH) * 32; \
        unsigned short* d_ = dA + (((2*(T)+(KH)) & 3) << 13); \
        gload_lds16(s_, d_); \
        gload_lds16(s_ + 16 * K, d_ + 512); } while (0)
#define STAGE_B(T, KH) do { \
        const unsigned short* s_ = srcB + (T) * 64 + (KH) * 32; \
        unsigned short* d_ = dB + (((2*(T)+(KH)) & 3) << 13); \
        gload_lds16(s_, d_); \
        gload_lds16(s_ + 16 * K, d_ + 512); } while (0)

    // prologue: tile0 k0,k1 + tile1 k0 = 6 halves (12 loads/wave).
    // vmcnt(8) -> oldest 2 halves (tile0 k0) landed before anyone reads them.
    STAGE_A(0, 0); STAGE_B(0, 0);
    STAGE_A(0, 1); STAGE_B(0, 1);
    STAGE_A(1, 0); STAGE_B(1, 0);
    asm volatile("s_waitcnt vmcnt(8)" ::: "memory");
    __builtin_amdgcn_s_barrier();

    bf16x8 aA[8], bB[2];
    for (int i = 0; i < NT / 2; ++i) {
        const int E = 2 * i, O = 2 * i + 1;
#pragma unroll
        for (int p = 0; p < 8; ++p) {
            const int T    = (p < 4) ? E : O;
            const int ks   = (p >> 1) & 1;
            const int nh   = p & 1;
            const int slot = (2 * T + ks) & 3;
            // T4: never drain; 3 half-tiles (6 loads) stay in flight.
            asm volatile("s_waitcnt vmcnt(6)" ::: "memory");
            if (nh == 0) {
#pragma unroll
                for (int m = 0; m < 8; ++m)
                    aA[m] = ld8(&lA[(slot << 13) + (wr * 64 + m * 8 + rp) * 64 + swzu]);
            }
#pragma unroll
            for (int nl = 0; nl < 2; ++nl)
                bB[nl] = ld8(&lB[(slot << 13) + (wc * 32 + nh * 16 + nl * 8 + rp) * 64 + swzu]);
            // stage one half-tile (consumed 6 phases later; slot freed >=1 phase ago)
            if      (p == 0) { STAGE_A(O, 1); }
            else if (p == 1) { STAGE_B(O, 1); }
            else if (p == 2) { if (E + 2 < NT) STAGE_A(E + 2, 0); }
            else if (p == 3) { if (E + 2 < NT) STAGE_B(E + 2, 0); }
            else if (p == 4) { if (E + 2 < NT) STAGE_A(E + 2, 1); }
            else if (p == 5) { if (E + 2 < NT) STAGE_B(E + 2, 1); }
            else if (p == 6) { if (O + 2 < NT) STAGE_A(O + 2, 0); }
            else             { if (O + 2 < NT) STAGE_B(O + 2, 0); }
            __builtin_amdgcn_s_barrier();
            asm volatile("s_waitcnt lgkmcnt(0)" ::: "memory");
            __builtin_amdgcn_sched_barrier(0);
            __builtin_amdgcn_s_setprio(1);
#pragma unroll
            for (int m = 0; m < 8; ++m)
#pragma unroll
                for (int nl = 0; nl < 2; ++nl)
                    acc[m][nh * 2 + nl] = __builtin_amdgcn_mfma_f32_16x16x32_bf16(
                        aA[m], bB[nl], acc[m][nh * 2 + nl], 0, 0, 0);
            __builtin_amdgcn_s_setprio(0);
            __builtin_amdgcn_s_barrier();
        }
    }
#undef STAGE_A
#undef STAGE_B

    // ---------------- epilogue ----------------
#pragma unroll
    for (int m = 0; m < 8; ++m) {
        const int rbase = blockM + wr * 128 + m * 16 + quad * 4;
#pragma unroll
        for (int n = 0; n < 4; ++n) {
            const int gcol = blockN + wc * 64 + n * 16 + lrow;
            const float bv = bias[gcol];
#pragma unroll
            for (int r = 0; r < 4; ++r) {
                const int row = rbase + r;
                float val = acc[m][n][r] + bv;
                if (EPI == 0) {
                    outp[(size_t)row * 1024 + gcol] = val;
                } else {
                    const int s = gcol >> 10;          // 0:q 1:k 2:v (uniform per wave)
                    const int cn = gcol & 1023;
                    const int h = cn >> 6, d = cn & 63;
                    const int b = row >> 11, t = row & 2047;
                    if (s < 2) {  // RoPE; pair element is in the adjacent lane
                        const int ii = d >> 1;
                        const float cz = tab[t * 64 + 2 * ii];
                        const float sz = tab[t * 64 + 2 * ii + 1];
                        const float pv = __shfl_xor(val, 1);
                        val = (d & 1) ? (pv * sz + val * cz) : (val * cz - pv * sz);
                    }
                    const unsigned short r16 = f2bf(val);
                    const size_t bhtd = (((size_t)(b * 16 + h)) * 2048 + t) * 64 + d;
                    if (s == 0) {
                        oq[bhtd] = r16;
                    } else if (s == 1) {
                        ok[bhtd] = r16;
                        cache[(((size_t)(b * 2 + 0)) * 2048 + t) * 1024 + h * 64 + d] = val;
                    } else {
                        ov[bhtd] = r16;
                        cache[(((size_t)(b * 2 + 1)) * 2048 + t) * 1024 + h * 64 + d] = val;
                    }
                }
            }
        }
    }
}

// ---------------- flash attention (causal), triangle-paired q-blocks ----------------
__global__ __launch_bounds__(256, 3) void k_attn(
    const unsigned short* __restrict__ qh,   // [B][H][T][64] bf16
    const unsigned short* __restrict__ kh,   // [B][H][T][64] bf16
    const unsigned short* __restrict__ vt,   // [B][H][64][T] bf16
    unsigned short* __restrict__ ctx)        // [B*T][1024]   bf16
{
    __shared__ __align__(16) unsigned short lK[2][64 * 64];
    __shared__ __align__(16) unsigned short lV[2][64 * 64];
    __shared__ __align__(16) unsigned short lP[4][32 * 68];
    const int tid = threadIdx.x;
    const int wave = tid >> 6, lane = tid & 63;
    const int lrow = lane & 15, quad = lane >> 4;
    const int sub = lane >> 3, g8 = lane & 7;
    const int grp = g8 ^ (sub & 7);
    const int pj = blockIdx.x;               // 0..7
    const int h = blockIdx.y, b = blockIdx.z;
    const unsigned short* Q  = qh + (size_t)(b * 16 + h) * 2048 * 64;
    const unsigned short* Kp = kh + (size_t)(b * 16 + h) * 2048 * 64;
    const unsigned short* Vt = vt + (size_t)(b * 16 + h) * 64 * 2048;

    bf16x8 bOnes;
#pragma unroll
    for (int j = 0; j < 8; ++j) bOnes[j] = (bf16_t)1.0f;

    for (int phase = 0; phase < 2; ++phase) {
        const int qb = phase ? pj : (15 - pj);
        const int qw = qb * 128 + wave * 32;     // this wave's first q row

        // Q fragments, pre-scaled by 1/sqrt(64)=0.125 (exact in bf16)
        bf16x8 aQ[2][2];
#pragma unroll
        for (int mf = 0; mf < 2; ++mf)
#pragma unroll
            for (int ks = 0; ks < 2; ++ks) {
                bf16x8 t = ld8(&Q[(size_t)(qw + mf * 16 + lrow) * 64 + ks * 32 + quad * 8]);
#pragma unroll
                for (int j = 0; j < 8; ++j) t[j] = (bf16_t)((float)t[j] * 0.125f);
                aQ[mf][ks] = t;
            }

        f32x4 o[2][4];
#pragma unroll
        for (int mf = 0; mf < 2; ++mf)
#pragma unroll
            for (int i = 0; i < 4; ++i) o[mf][i] = (f32x4){0.f, 0.f, 0.f, 0.f};
        f32x4 lacc[2];
        lacc[0] = (f32x4){0.f, 0.f, 0.f, 0.f};
        lacc[1] = (f32x4){0.f, 0.f, 0.f, 0.f};

        const int nT = 2 * (qb + 1);             // 64-col tiles this phase needs

        __syncthreads();   // protect lK/lV from previous phase's readers
        // prefetch tile 0 into buf 0 (4 issues/wave: 2 K chunks + 2 V chunks)
#pragma unroll
        for (int i = 0; i < 2; ++i) {
            const int c = wave * 2 + i;
            gload_lds16(&Kp[(size_t)(c * 8 + sub) * 64 + grp * 8], &lK[0][c * 512]);
            gload_lds16(&Vt[(size_t)(c * 8 + sub) * 2048 + grp * 8], &lV[0][c * 512]);
        }

        int buf = 0;
        for (int it = 0; it < nT; ++it) {
            const int kt0 = it * 64;
            __syncthreads();   // staged buf visible to all; prev compute done
            if (it + 1 < nT) {
                const int kn = kt0 + 64;
#pragma unroll
                for (int i = 0; i < 2; ++i) {
                    const int c = wave * 2 + i;
                    gload_lds16(&Kp[(size_t)(kn + c * 8 + sub) * 64 + grp * 8], &lK[buf ^ 1][c * 512]);
                    gload_lds16(&Vt[(size_t)(c * 8 + sub) * 2048 + kn + grp * 8], &lV[buf ^ 1][c * 512]);
                }
            }
            if (kt0 < qw + 32) {
                const unsigned short* lKb = lK[buf];
                const unsigned short* lVb = lV[buf];
                f32x4 s[2][4];
#pragma unroll
                for (int mf = 0; mf < 2; ++mf)
#pragma unroll
                    for (int i = 0; i < 4; ++i) s[mf][i] = (f32x4){0.f, 0.f, 0.f, 0.f};
#pragma unroll
                for (int nt = 0; nt < 4; ++nt) {
                    const int row = nt * 16 + lrow;
#pragma unroll
                    for (int ks = 0; ks < 2; ++ks) {
                        bf16x8 bK = ld8(&lKb[row * 64 + (((ks * 4 + quad) ^ (row & 7)) * 8)]);
#pragma unroll
                        for (int mf = 0; mf < 2; ++mf)
                            s[mf][nt] = __builtin_amdgcn_mfma_f32_16x16x32_bf16(
                                aQ[mf][ks], bK, s[mf][nt], 0, 0, 0);
                    }
                }
                // p = exp(s); only the diagonal tile needs the causal mask
                if (kt0 + 63 > qw) {
#pragma unroll
                    for (int mf = 0; mf < 2; ++mf)
#pragma unroll
                        for (int nt = 0; nt < 4; ++nt) {
                            const int colg = kt0 + nt * 16 + lrow;
#pragma unroll
                            for (int r = 0; r < 4; ++r) {
                                const int rowg = qw + mf * 16 + quad * 4 + r;
                                const float pv = (colg <= rowg) ? __expf(s[mf][nt][r]) : 0.f;
                                lP[wave][(mf * 16 + quad * 4 + r) * 68 + nt * 16 + lrow] = f2bf(pv);
                            }
                        }
                } else {
#pragma unroll
                    for (int mf = 0; mf < 2; ++mf)
#pragma unroll
                        for (int nt = 0; nt < 4; ++nt)
#pragma unroll
                            for (int r = 0; r < 4; ++r)
                                lP[wave][(mf * 16 + quad * 4 + r) * 68 + nt * 16 + lrow] =
                                    f2bf(__expf(s[mf][nt][r]));
                }
                bf16x8 aP[2][2];
#pragma unroll
                for (int mf = 0; mf < 2; ++mf)
#pragma unroll
                    for (int ks = 0; ks < 2; ++ks)
                        aP[mf][ks] = ld8(&lP[wave][(mf * 16 + lrow) * 68 + ks * 32 + quad * 8]);
#pragma unroll
                for (int mf = 0; mf < 2; ++mf)
#pragma unroll
                    for (int ks = 0; ks < 2; ++ks)
                        lacc[mf] = __builtin_amdgcn_mfma_f32_16x16x32_bf16(
                            aP[mf][ks], bOnes, lacc[mf], 0, 0, 0);
#pragma unroll
                for (int dt = 0; dt < 4; ++dt) {
                    const int row = dt * 16 + lrow;
#pragma unroll
                    for (int ks = 0; ks < 2; ++ks) {
                        bf16x8 bV = ld8(&lVb[row * 64 + (((ks * 4 + quad) ^ (row & 7)) * 8)]);
#pragma unroll
                        for (int mf = 0; mf < 2; ++mf)
                            o[mf][dt] = __builtin_amdgcn_mfma_f32_16x16x32_bf16(
                                aP[mf][ks], bV, o[mf][dt], 0, 0, 0);
                    }
                }
            }
            buf ^= 1;
        }

        float inv[2][4];
#pragma unroll
        for (int mf = 0; mf < 2; ++mf)
#pragma unroll
            for (int r = 0; r < 4; ++r) inv[mf][r] = 1.0f / lacc[mf][r];
#pragma unroll
        for (int mf = 0; mf < 2; ++mf)
#pragma unroll
            for (int dt = 0; dt < 4; ++dt) {
                const int col = h * 64 + dt * 16 + lrow;
#pragma unroll
                for (int r = 0; r < 4; ++r) {
                    const int trow = qw + mf * 16 + quad * 4 + r;
                    ctx[((size_t)(b * 2048 + trow)) * 1024 + col] = f2bf(o[mf][dt][r] * inv[mf][r]);
                }
            }
    }
}

extern "C" void kernel_launch(void* const* d_in, const int* in_sizes, int n_in,
                              void* d_out, int out_size, void* d_ws, size_t ws_size,
                              hipStream_t stream) {
    (void)in_sizes; (void)n_in; (void)out_size; (void)ws_size;
    const float* x    = (const float*)d_in[0];
    const float* wqkv = (const float*)d_in[1];
    const float* bqkv = (const float*)d_in[2];
    const float* wout = (const float*)d_in[3];
    const float* bout = (const float*)d_in[4];
    const int*   offp = (const int*)d_in[5];

    float* out   = (float*)d_out;
    float* cache = out + (size_t)2 * 2048 * 1024;   // 4,194,304 fp32 elems

    char* w = (char*)d_ws;
    float* tab            = (float*)w;          w += (size_t)2048 * 64 * sizeof(float);
    unsigned short* xb    = (unsigned short*)w; w += (size_t)4194304 * 2;
    unsigned short* wqkvT = (unsigned short*)w; w += (size_t)3072 * 1024 * 2;
    unsigned short* woutT = (unsigned short*)w; w += (size_t)1024 * 1024 * 2;
    unsigned short* qh    = (unsigned short*)w; w += (size_t)4194304 * 2;
    unsigned short* kh    = (unsigned short*)w; w += (size_t)4194304 * 2;
    unsigned short* vh    = (unsigned short*)w; w += (size_t)4194304 * 2;
    unsigned short* vt    = (unsigned short*)w; w += (size_t)4194304 * 2;
    unsigned short* ctx   = (unsigned short*)w; w += (size_t)4194304 * 2;

    k_ropetab<<<dim3(256), dim3(256), 0, stream>>>(tab, offp);
    // x fp32 [4096][1024] -> xb bf16
    k_cvt<<<dim3(2048), dim3(256), 0, stream>>>(x, xb);
    // Wqkv fp32 [1024][3072] -> WqkvT bf16 [3072][1024]
    k_transposeF2B<<<dim3(48, 16, 1), dim3(256), 0, stream>>>(wqkv, wqkvT, 1024, 3072);
    // Wout fp32 [1024][1024] -> WoutT bf16 [1024][1024]
    k_transposeF2B<<<dim3(16, 16, 1), dim3(256), 0, stream>>>(wout, woutT, 1024, 1024);
    // QKV projection + bias + RoPE + scatter: 256x256 tiles -> grid (3072/256, 4096/256)
    k_gemm<1><<<dim3(12, 16), dim3(512), 0, stream>>>(xb, wqkvT, bqkv, tab, qh, kh, vh, cache, nullptr);
    // V bf16 [bh][2048][64] -> Vt bf16 [bh][64][2048]
    k_transpose64<<<dim3(1, 32, 32), dim3(256), 0, stream>>>(vh, vt, 2048, 64);
    // flash attention -> ctx bf16 (triangle-paired: 256 blocks, 17 units each)
    k_attn<<<dim3(8, 16, 2), dim3(256), 0, stream>>>(qh, kh, vt, ctx);
    // out projection -> fp32 out: grid (1024/256, 4096/256)
    k_gemm<0><<<dim3(4, 16), dim3(512), 0, stream>>>(ctx, woutT, bout, tab, nullptr, nullptr, nullptr, nullptr, out);
}

// Round 2
// 256.382 us; speedup vs baseline: 1.0068x; 1.0068x over previous
//
#include <hip/hip_runtime.h>
#include <stdint.h>
#include <math.h>

// Problem: B=2, T=2048, H=16, hd=64, D=1024, 3D=3072
// I/O dtype: float32 (per reference). Internal MFMA pipeline: bf16.
// d_out: [out (2,2048,1024)] ++ [new_cache (2,2,2048,16,64)], fp32
// d_in: x, Wqkv, bqkv, Wout, bout (fp32), offset (int32)

typedef __bf16 bf16_t;
typedef bf16_t bf16x8 __attribute__((ext_vector_type(8)));
typedef float f32x4 __attribute__((ext_vector_type(4)));
typedef unsigned short ushort8_t __attribute__((ext_vector_type(8)));

__device__ __forceinline__ unsigned short f2bf(float f) {
    union { float f; unsigned int i; } v; v.f = f;
    unsigned int r = v.i + 0x7fffu + ((v.i >> 16) & 1u);
    return (unsigned short)(r >> 16);
}
__device__ __forceinline__ bf16x8 ld8(const unsigned short* p) {
    return *(const bf16x8*)p;
}
__device__ __forceinline__ void gload_lds16(const unsigned short* g, unsigned short* l) {
    __builtin_amdgcn_global_load_lds(
        (__attribute__((address_space(1))) void*)(g),
        (__attribute__((address_space(3))) void*)(l),
        16, 0, 0);
}

// ---------------- fp32 -> bf16 bulk convert (8 elems/thread) ----------------
__global__ void k_cvt(const float* __restrict__ in, unsigned short* __restrict__ out) {
    const int i = (blockIdx.x * 256 + threadIdx.x) * 8;
    float4 a = *(const float4*)&in[i];
    float4 b = *(const float4*)&in[i + 4];
    ushort8_t v;
    v[0] = f2bf(a.x); v[1] = f2bf(a.y); v[2] = f2bf(a.z); v[3] = f2bf(a.w);
    v[4] = f2bf(b.x); v[5] = f2bf(b.y); v[6] = f2bf(b.z); v[7] = f2bf(b.w);
    *(ushort8_t*)&out[i] = v;
}

// ---------------- RoPE cos/sin table: tab[t][i][2], t<2048, i<32 ----------------
__global__ void k_ropetab(float* __restrict__ tab, const int* __restrict__ offp) {
    int idx = blockIdx.x * blockDim.x + threadIdx.x;   // 65536 threads
    int t = idx >> 5, i = idx & 31;
    float off = (float)(*offp);
    float inv = powf(10000.0f, -(float)(2 * i) / 64.0f);
    float ang = ((float)t + off) * inv;
    float s, c;
    sincosf(ang, &s, &c);
    tab[idx * 2]     = c;
    tab[idx * 2 + 1] = s;
}

// ------- 64x64 tile transpose + downconvert: in fp32 [bz][R][C] -> out bf16 [bz][C][R] -------
__global__ void k_transposeF2B(const float* __restrict__ in,
                               unsigned short* __restrict__ out, int R, int C) {
    __shared__ __align__(16) float tile[64 * 68];
    const int bz = blockIdx.z;
    const size_t base = (size_t)bz * R * C;
    const int tR = blockIdx.y * 64, tC = blockIdx.x * 64;
    const int tid = threadIdx.x;
#pragma unroll
    for (int it = 0; it < 4; ++it) {
        int flat = (it * 256 + tid) * 4;
        int r = flat >> 6, c = flat & 63;
        *(float4*)&tile[r * 68 + c] =
            *(const float4*)&in[base + (size_t)(tR + r) * C + tC + c];
    }
    __syncthreads();
#pragma unroll
    for (int it = 0; it < 2; ++it) {
        int flat = (it * 256 + tid) * 8;
        int rr = flat >> 6, cc = flat & 63;
        ushort8_t v;
#pragma unroll
        for (int j = 0; j < 8; ++j) v[j] = f2bf(tile[(cc + j) * 68 + rr]);
        *(ushort8_t*)&out[base + (size_t)(tC + rr) * R + tR + cc] = v;
    }
}

// ---------------- batched bf16 64x64 tile transpose: in[bz][R][C] -> out[bz][C][R] ----------------
__global__ void k_transpose64(const unsigned short* __restrict__ in,
                              unsigned short* __restrict__ out, int R, int C) {
    __shared__ __align__(16) unsigned short tile[64 * 72];
    const int bz = blockIdx.z;
    const size_t base = (size_t)bz * R * C;
    const int tR = blockIdx.y * 64, tC = blockIdx.x * 64;
    const int tid = threadIdx.x;
#pragma unroll
    for (int it = 0; it < 2; ++it) {
        int flat = (it * 256 + tid) * 8;
        int r = flat >> 6, c = flat & 63;
        *(ushort8_t*)&tile[r * 72 + c] =
            *(const ushort8_t*)&in[base + (size_t)(tR + r) * C + tC + c];
    }
    __syncthreads();
#pragma unroll
    for (int it = 0; it < 2; ++it) {
        int flat = (it * 256 + tid) * 8;
        int rr = flat >> 6, cc = flat & 63;
        ushort8_t v;
#pragma unroll
        for (int j = 0; j < 8; ++j) v[j] = tile[(cc + j) * 72 + rr];
        *(ushort8_t*)&out[base + (size_t)(tC + rr) * R + tR + cc] = v;
    }
}

// ================= 256x256 MFMA GEMM, K=1024, BK=64, 8-wave, 8-phase schedule =================
// T1 XCD swizzle; T2 LDS XOR swizzle (linear gload_lds dest, pre-swizzled global src);
// T3/T4 4-slot half-tile ring, stagger: A-half of slot s staged at phase 2s+1,
//   B-half at 2s+2 (mod 8) -> stage->read lead 7 (A) / 6 (B) phases.
//   vmcnt(6) at EVEN phases only (fix of round-1's every-phase vmcnt(6) throttle,
//   which capped in-flight at 3 phases < load latency and stalled every phase).
//   Steady state: outstanding at each wait = 10 loads, forces the 2 oldest halves
//   -> every slot is force-completed >=2 barrier-separated phases before its read.
//   Final iteration peeled with waits 6/2/0 so the drained tail is race-free.
// T5 setprio(1) around each 16-MFMA cluster.
template <int EPI>
__global__ __launch_bounds__(512, 2) void k_gemm(
    const unsigned short* __restrict__ A,
    const unsigned short* __restrict__ Bt,
    const float* __restrict__ bias,
    const float* __restrict__ tab,
    unsigned short* __restrict__ oq,
    unsigned short* __restrict__ ok,
    unsigned short* __restrict__ ov,
    float* __restrict__ cache,
    float* __restrict__ outp)
{
    constexpr int K = 1024;
    __shared__ __align__(16) unsigned short lds[65536];   // 128 KiB
    unsigned short* lA = lds;                    // 4 slots x 8192 ushorts (16 KB)
    unsigned short* lB = lds + 32768;

    const int tid  = threadIdx.x;
    const int lane = tid & 63, w = tid >> 6;
    const int wr = w >> 2, wc = w & 3;           // 2 x 4 wave grid
    const int lrow = lane & 15, quad = lane >> 4;

    // --- T1: XCD-aware bijective swizzle (nwg % 8 == 0 for both launches) ---
    const int gx  = gridDim.x;
    const int nwg = gx * gridDim.y;
    const int bid = blockIdx.y * gx + blockIdx.x;
    const int sw  = (bid & 7) * (nwg >> 3) + (bid >> 3);
    const int blockM = (sw / gx) * 256;
    const int blockN = (sw % gx) * 256;

    // --- staging: linear LDS dest, pre-swizzled global source (T2, rule #21) ---
    const int q8    = (lane & 7) ^ (lane >> 3);
    const int srow0 = ((w * 16 + (lane >> 3)) << 1) + ((q8 >> 2) & 1);
    const int scol  = (q8 & 3) * 8;
    const unsigned short* srcA = A  + (size_t)(blockM + srow0) * K + scol;
    const unsigned short* srcB = Bt + (size_t)(blockN + srow0) * K + scol;
    unsigned short* dA = lA + w * 1024;          // + slot*8192 at use
    unsigned short* dB = lB + w * 1024;

    // --- frag reads: same XOR on the read side -> 2-way bank conflict (free) ---
    const int rp   = lrow >> 1;
    const int swzu = ((((lane & 1) << 6) | (quad << 4)) ^ (rp << 4)) >> 1;

    f32x4 acc[8][4];
#pragma unroll
    for (int m = 0; m < 8; ++m)
#pragma unroll
        for (int n = 0; n < 4; ++n) acc[m][n] = (f32x4){0.f, 0.f, 0.f, 0.f};

#define STAGE_A(T, KH) do { \
        const unsigned short* s_ = srcA + (T) * 64 + (KH) * 32; \
        unsigned short* d_ = dA + (((2*(T)+(KH)) & 3) << 13); \
        gload_lds16(s_, d_); \
        gload_lds16(s_ + 16 * K, d_ + 512); } while (0)
#define STAGE_B(T, KH) do { \
        const unsigned short* s_ = srcB + (T) * 64 + (KH) * 32; \
        unsigned short* d_ = dB + (((2*(T)+(KH)) & 3) << 13); \
        gload_lds16(s_, d_); \
        gload_lds16(s_ + 16 * K, d_ + 512); } while (0)
#define WAITN(n) asm volatile("s_waitcnt vmcnt(" #n ")" ::: "memory")
#define RD_A(slot) do { \
        _Pragma("unroll") \
        for (int m = 0; m < 8; ++m) \
            aA[m] = ld8(&lA[((slot) << 13) + (wr * 64 + m * 8 + rp) * 64 + swzu]); } while (0)
#define RD_B(slot, nh) do { \
        _Pragma("unroll") \
        for (int nl = 0; nl < 2; ++nl) \
            bB[nl] = ld8(&lB[((slot) << 13) + (wc * 32 + (nh) * 16 + nl * 8 + rp) * 64 + swzu]); } while (0)
#define MFMA16(nh) do { \
        __builtin_amdgcn_s_barrier(); \
        asm volatile("s_waitcnt lgkmcnt(0)" ::: "memory"); \
        __builtin_amdgcn_sched_barrier(0); \
        __builtin_amdgcn_s_setprio(1); \
        _Pragma("unroll") \
        for (int m = 0; m < 8; ++m) { \
            acc[m][(nh)*2+0] = __builtin_amdgcn_mfma_f32_16x16x32_bf16(aA[m], bB[0], acc[m][(nh)*2+0], 0, 0, 0); \
            acc[m][(nh)*2+1] = __builtin_amdgcn_mfma_f32_16x16x32_bf16(aA[m], bB[1], acc[m][(nh)*2+1], 0, 0, 0); } \
        __builtin_amdgcn_s_setprio(0); \
        __builtin_amdgcn_s_barrier(); } while (0)

    // prologue: 7 halves (14 loads), oldest-first = A0,B0,A1,B1,A2,B2,A3
    STAGE_A(0, 0); STAGE_B(0, 0);
    STAGE_A(0, 1); STAGE_B(0, 1);
    STAGE_A(1, 0); STAGE_B(1, 0);
    STAGE_A(1, 1);
    asm volatile("s_waitcnt vmcnt(8)" ::: "memory");   // forces A0,B0,A1
    __builtin_amdgcn_s_barrier();

    bf16x8 aA[8], bB[2];
    for (int i = 0; i < 7; ++i) {
        const int E = 2 * i, O = 2 * i + 1;
        WAITN(6); RD_A(0); RD_B(0, 0); STAGE_B(O, 1);     MFMA16(0);   // p0
        RD_B(0, 1);                    STAGE_A(E + 2, 0); MFMA16(1);   // p1
        WAITN(6); RD_A(1); RD_B(1, 0); STAGE_B(E + 2, 0); MFMA16(0);   // p2
        RD_B(1, 1);                    STAGE_A(E + 2, 1); MFMA16(1);   // p3
        WAITN(6); RD_A(2); RD_B(2, 0); STAGE_B(E + 2, 1); MFMA16(0);   // p4
        RD_B(2, 1);                    STAGE_A(O + 2, 0); MFMA16(1);   // p5
        WAITN(6); RD_A(3); RD_B(3, 0); STAGE_B(O + 2, 0); MFMA16(0);   // p6
        RD_B(3, 1);                    STAGE_A(O + 2, 1); MFMA16(1);   // p7
    }
    // final iteration (E=14, O=15): only B-slot3 still to stage; draining waits
    WAITN(6); RD_A(0); RD_B(0, 0); STAGE_B(15, 1); MFMA16(0);
    RD_B(0, 1);                                    MFMA16(1);
    WAITN(2); RD_A(1); RD_B(1, 0);                 MFMA16(0);
    RD_B(1, 1);                                    MFMA16(1);
    WAITN(0); RD_A(2); RD_B(2, 0);                 MFMA16(0);
    RD_B(2, 1);                                    MFMA16(1);
    RD_A(3); RD_B(3, 0);                           MFMA16(0);
    RD_B(3, 1);                                    MFMA16(1);
#undef STAGE_A
#undef STAGE_B
#undef WAITN
#undef RD_A
#undef RD_B
#undef MFMA16

    // ---------------- epilogue ----------------
#pragma unroll
    for (int m = 0; m < 8; ++m) {
        const int rbase = blockM + wr * 128 + m * 16 + quad * 4;
#pragma unroll
        for (int n = 0; n < 4; ++n) {
            const int gcol = blockN + wc * 64 + n * 16 + lrow;
            const float bv = bias[gcol];
#pragma unroll
            for (int r = 0; r < 4; ++r) {
                const int row = rbase + r;
                float val = acc[m][n][r] + bv;
                if (EPI == 0) {
                    outp[(size_t)row * 1024 + gcol] = val;
                } else {
                    const int s = gcol >> 10;          // 0:q 1:k 2:v (uniform per block)
                    const int cn = gcol & 1023;
                    const int h = cn >> 6, d = cn & 63;
                    const int b = row >> 11, t = row & 2047;
                    if (s < 2) {  // RoPE; pair element is in the adjacent lane
                        const int ii = d >> 1;
                        const float cz = tab[t * 64 + 2 * ii];
                        const float sz = tab[t * 64 + 2 * ii + 1];
                        const float pv = __shfl_xor(val, 1);
                        val = (d & 1) ? (pv * sz + val * cz) : (val * cz - pv * sz);
                    }
                    const unsigned short r16 = f2bf(val);
                    const size_t bhtd = (((size_t)(b * 16 + h)) * 2048 + t) * 64 + d;
                    if (s == 0) {
                        oq[bhtd] = r16;
                    } else if (s == 1) {
                        ok[bhtd] = r16;
                        cache[(((size_t)(b * 2 + 0)) * 2048 + t) * 1024 + h * 64 + d] = val;
                    } else {
                        ov[bhtd] = r16;
                        cache[(((size_t)(b * 2 + 1)) * 2048 + t) * 1024 + h * 64 + d] = val;
                    }
                }
            }
        }
    }
}

// ---------------- flash attention (causal), merged triangle pair, 8 waves ----------------
// Round-1 counters: Occupancy 10.3% = 1 wave/SIMD -> MFMA pipe idle on every stall.
// Merge the two triangle phases into one 512-thread block: waves 0-3 own q-block
// (15-pj), waves 4-7 own q-block pj. pj's K/V tile range is a strict prefix of
// (15-pj)'s, so ONE staging pass over nT = 2*(16-pj) tiles serves both ->
// 2 waves/SIMD, staged K/V traffic drops 34 -> 2*(16-pj) tiles/block, and per-block
// cost stays uniform: 2(pj+1) tiles x 8 waves + rest x 4 waves = 34 wave-units.
__global__ __launch_bounds__(512, 2) void k_attn(
    const unsigned short* __restrict__ qh,   // [B][H][T][64] bf16
    const unsigned short* __restrict__ kh,   // [B][H][T][64] bf16
    const unsigned short* __restrict__ vt,   // [B][H][64][T] bf16
    unsigned short* __restrict__ ctx)        // [B*T][1024]   bf16
{
    __shared__ __align__(16) unsigned short lK[2][64 * 64];
    __shared__ __align__(16) unsigned short lV[2][64 * 64];
    __shared__ __align__(16) unsigned short lP[8][32 * 68];
    const int tid = threadIdx.x;
    const int wave = tid >> 6, lane = tid & 63;
    const int lrow = lane & 15, quad = lane >> 4;
    const int sub = lane >> 3, g8 = lane & 7;
    const int grp = g8 ^ (sub & 7);
    const int pj = blockIdx.x;               // 0..7
    const int h = blockIdx.y, b = blockIdx.z;
    const unsigned short* Q  = qh + (size_t)(b * 16 + h) * 2048 * 64;
    const unsigned short* Kp = kh + (size_t)(b * 16 + h) * 2048 * 64;
    const unsigned short* Vt = vt + (size_t)(b * 16 + h) * 64 * 2048;

    const int grpq = wave >> 2;              // 0: long q-block, 1: short
    const int wv   = wave & 3;
    const int qb   = grpq ? pj : (15 - pj);
    const int qw   = qb * 128 + wv * 32;     // this wave's first q row
    const int nT   = 2 * (16 - pj);          // 64-col K/V tiles staged (covers both groups)

    bf16x8 bOnes;
#pragma unroll
    for (int j = 0; j < 8; ++j) bOnes[j] = (bf16_t)1.0f;

    // Q fragments, pre-scaled by 1/sqrt(64)=0.125 (exact in bf16)
    bf16x8 aQ[2][2];
#pragma unroll
    for (int mf = 0; mf < 2; ++mf)
#pragma unroll
        for (int ks = 0; ks < 2; ++ks) {
            bf16x8 t = ld8(&Q[(size_t)(qw + mf * 16 + lrow) * 64 + ks * 32 + quad * 8]);
#pragma unroll
            for (int j = 0; j < 8; ++j) t[j] = (bf16_t)((float)t[j] * 0.125f);
            aQ[mf][ks] = t;
        }

    f32x4 o[2][4];
#pragma unroll
    for (int mf = 0; mf < 2; ++mf)
#pragma unroll
        for (int i = 0; i < 4; ++i) o[mf][i] = (f32x4){0.f, 0.f, 0.f, 0.f};
    f32x4 lacc[2];
    lacc[0] = (f32x4){0.f, 0.f, 0.f, 0.f};
    lacc[1] = (f32x4){0.f, 0.f, 0.f, 0.f};

    // prefetch tile 0 into buf 0 (2 issues/wave: 1 K chunk + 1 V chunk)
    {
        const int c = wave;
        gload_lds16(&Kp[(size_t)(c * 8 + sub) * 64 + grp * 8], &lK[0][c * 512]);
        gload_lds16(&Vt[(size_t)(c * 8 + sub) * 2048 + grp * 8], &lV[0][c * 512]);
    }

    int buf = 0;
    for (int it = 0; it < nT; ++it) {
        const int kt0 = it * 64;
        __syncthreads();   // staged buf visible to all; prev compute done
        if (it + 1 < nT) {
            const int kn = kt0 + 64;
            const int c = wave;
            gload_lds16(&Kp[(size_t)(kn + c * 8 + sub) * 64 + grp * 8], &lK[buf ^ 1][c * 512]);
            gload_lds16(&Vt[(size_t)(c * 8 + sub) * 2048 + kn + grp * 8], &lV[buf ^ 1][c * 512]);
        }
        if (kt0 < qw + 32) {
            const unsigned short* lKb = lK[buf];
            const unsigned short* lVb = lV[buf];
            f32x4 s[2][4];
#pragma unroll
            for (int mf = 0; mf < 2; ++mf)
#pragma unroll
                for (int i = 0; i < 4; ++i) s[mf][i] = (f32x4){0.f, 0.f, 0.f, 0.f};
#pragma unroll
            for (int nt = 0; nt < 4; ++nt) {
                const int row = nt * 16 + lrow;
#pragma unroll
                for (int ks = 0; ks < 2; ++ks) {
                    bf16x8 bK = ld8(&lKb[row * 64 + (((ks * 4 + quad) ^ (row & 7)) * 8)]);
#pragma unroll
                    for (int mf = 0; mf < 2; ++mf)
                        s[mf][nt] = __builtin_amdgcn_mfma_f32_16x16x32_bf16(
                            aQ[mf][ks], bK, s[mf][nt], 0, 0, 0);
                }
            }
            // p = exp(s); only the diagonal tile needs the causal mask
            if (kt0 + 63 > qw) {
#pragma unroll
                for (int mf = 0; mf < 2; ++mf)
#pragma unroll
                    for (int nt = 0; nt < 4; ++nt) {
                        const int colg = kt0 + nt * 16 + lrow;
#pragma unroll
                        for (int r = 0; r < 4; ++r) {
                            const int rowg = qw + mf * 16 + quad * 4 + r;
                            const float pv = (colg <= rowg) ? __expf(s[mf][nt][r]) : 0.f;
                            lP[wave][(mf * 16 + quad * 4 + r) * 68 + nt * 16 + lrow] = f2bf(pv);
                        }
                    }
            } else {
#pragma unroll
                for (int mf = 0; mf < 2; ++mf)
#pragma unroll
                    for (int nt = 0; nt < 4; ++nt)
#pragma unroll
                        for (int r = 0; r < 4; ++r)
                            lP[wave][(mf * 16 + quad * 4 + r) * 68 + nt * 16 + lrow] =
                                f2bf(__expf(s[mf][nt][r]));
            }
            bf16x8 aP[2][2];
#pragma unroll
            for (int mf = 0; mf < 2; ++mf)
#pragma unroll
                for (int ks = 0; ks < 2; ++ks)
                    aP[mf][ks] = ld8(&lP[wave][(mf * 16 + lrow) * 68 + ks * 32 + quad * 8]);
#pragma unroll
            for (int mf = 0; mf < 2; ++mf)
#pragma unroll
                for (int ks = 0; ks < 2; ++ks)
                    lacc[mf] = __builtin_amdgcn_mfma_f32_16x16x32_bf16(
                        aP[mf][ks], bOnes, lacc[mf], 0, 0, 0);
#pragma unroll
            for (int dt = 0; dt < 4; ++dt) {
                const int row = dt * 16 + lrow;
#pragma unroll
                for (int ks = 0; ks < 2; ++ks) {
                    bf16x8 bV = ld8(&lVb[row * 64 + (((ks * 4 + quad) ^ (row & 7)) * 8)]);
#pragma unroll
                    for (int mf = 0; mf < 2; ++mf)
                        o[mf][dt] = __builtin_amdgcn_mfma_f32_16x16x32_bf16(
                            aP[mf][ks], bV, o[mf][dt], 0, 0, 0);
                }
            }
        }
        buf ^= 1;
    }

    float inv[2][4];
#pragma unroll
    for (int mf = 0; mf < 2; ++mf)
#pragma unroll
        for (int r = 0; r < 4; ++r) inv[mf][r] = 1.0f / lacc[mf][r];
#pragma unroll
    for (int mf = 0; mf < 2; ++mf)
#pragma unroll
        for (int dt = 0; dt < 4; ++dt) {
            const int col = h * 64 + dt * 16 + lrow;
#pragma unroll
            for (int r = 0; r < 4; ++r) {
                const int trow = qw + mf * 16 + quad * 4 + r;
                ctx[((size_t)(b * 2048 + trow)) * 1024 + col] = f2bf(o[mf][dt][r] * inv[mf][r]);
            }
        }
}

extern "C" void kernel_launch(void* const* d_in, const int* in_sizes, int n_in,
                              void* d_out, int out_size, void* d_ws, size_t ws_size,
                              hipStream_t stream) {
    (void)in_sizes; (void)n_in; (void)out_size; (void)ws_size;
    const float* x    = (const float*)d_in[0];
    const float* wqkv = (const float*)d_in[1];
    const float* bqkv = (const float*)d_in[2];
    const float* wout = (const float*)d_in[3];
    const float* bout = (const float*)d_in[4];
    const int*   offp = (const int*)d_in[5];

    float* out   = (float*)d_out;
    float* cache = out + (size_t)2 * 2048 * 1024;   // 4,194,304 fp32 elems

    char* w = (char*)d_ws;
    float* tab            = (float*)w;          w += (size_t)2048 * 64 * sizeof(float);
    unsigned short* xb    = (unsigned short*)w; w += (size_t)4194304 * 2;
    unsigned short* wqkvT = (unsigned short*)w; w += (size_t)3072 * 1024 * 2;
    unsigned short* woutT = (unsigned short*)w; w += (size_t)1024 * 1024 * 2;
    unsigned short* qh    = (unsigned short*)w; w += (size_t)4194304 * 2;
    unsigned short* kh    = (unsigned short*)w; w += (size_t)4194304 * 2;
    unsigned short* vh    = (unsigned short*)w; w += (size_t)4194304 * 2;
    unsigned short* vt    = (unsigned short*)w; w += (size_t)4194304 * 2;
    unsigned short* ctx   = (unsigned short*)w; w += (size_t)4194304 * 2;

    k_ropetab<<<dim3(256), dim3(256), 0, stream>>>(tab, offp);
    // x fp32 [4096][1024] -> xb bf16
    k_cvt<<<dim3(2048), dim3(256), 0, stream>>>(x, xb);
    // Wqkv fp32 [1024][3072] -> WqkvT bf16 [3072][1024]
    k_transposeF2B<<<dim3(48, 16, 1), dim3(256), 0, stream>>>(wqkv, wqkvT, 1024, 3072);
    // Wout fp32 [1024][1024] -> WoutT bf16 [1024][1024]
    k_transposeF2B<<<dim3(16, 16, 1), dim3(256), 0, stream>>>(wout, woutT, 1024, 1024);
    // QKV projection + bias + RoPE + scatter: 256x256 tiles -> grid (3072/256, 4096/256)
    k_gemm<1><<<dim3(12, 16), dim3(512), 0, stream>>>(xb, wqkvT, bqkv, tab, qh, kh, vh, cache, nullptr);
    // V bf16 [bh][2048][64] -> Vt bf16 [bh][64][2048]
    k_transpose64<<<dim3(1, 32, 32), dim3(256), 0, stream>>>(vh, vt, 2048, 64);
    // flash attention -> ctx bf16 (merged triangle pair: 256 blocks x 8 waves, 34 units each)
    k_attn<<<dim3(8, 16, 2), dim3(512), 0, stream>>>(qh, kh, vt, ctx);
    // out projection -> fp32 out: grid (1024/256, 4096/256)
    k_gemm<0><<<dim3(4, 16), dim3(512), 0, stream>>>(ctx, woutT, bout, tab, nullptr, nullptr, nullptr, nullptr, out);
}

// Round 3
// 250.219 us; speedup vs baseline: 1.0316x; 1.0246x over previous
//
#include <hip/hip_runtime.h>
#include <stdint.h>
#include <math.h>

// Problem: B=2, T=2048, H=16, hd=64, D=1024, 3D=3072
// I/O dtype: float32 (per reference). Internal MFMA pipeline: bf16.
// d_out: [out (2,2048,1024)] ++ [new_cache (2,2,2048,16,64)], fp32
// d_in: x, Wqkv, bqkv, Wout, bout (fp32), offset (int32)

typedef __bf16 bf16_t;
typedef bf16_t bf16x8 __attribute__((ext_vector_type(8)));
typedef float f32x4 __attribute__((ext_vector_type(4)));
typedef unsigned short ushort8_t __attribute__((ext_vector_type(8)));

__device__ __forceinline__ unsigned short f2bf(float f) {
    union { float f; unsigned int i; } v; v.f = f;
    unsigned int r = v.i + 0x7fffu + ((v.i >> 16) & 1u);
    return (unsigned short)(r >> 16);
}
__device__ __forceinline__ bf16x8 ld8(const unsigned short* p) {
    return *(const bf16x8*)p;
}
__device__ __forceinline__ void gload_lds16(const unsigned short* g, unsigned short* l) {
    __builtin_amdgcn_global_load_lds(
        (__attribute__((address_space(1))) void*)(g),
        (__attribute__((address_space(3))) void*)(l),
        16, 0, 0);
}

// ---------------- fp32 -> bf16 bulk convert (8 elems/thread) ----------------
__global__ void k_cvt(const float* __restrict__ in, unsigned short* __restrict__ out) {
    const int i = (blockIdx.x * 256 + threadIdx.x) * 8;
    float4 a = *(const float4*)&in[i];
    float4 b = *(const float4*)&in[i + 4];
    ushort8_t v;
    v[0] = f2bf(a.x); v[1] = f2bf(a.y); v[2] = f2bf(a.z); v[3] = f2bf(a.w);
    v[4] = f2bf(b.x); v[5] = f2bf(b.y); v[6] = f2bf(b.z); v[7] = f2bf(b.w);
    *(ushort8_t*)&out[i] = v;
}

// ---------------- RoPE cos/sin table: tab[t][i][2], t<2048, i<32 ----------------
__global__ void k_ropetab(float* __restrict__ tab, const int* __restrict__ offp) {
    int idx = blockIdx.x * blockDim.x + threadIdx.x;   // 65536 threads
    int t = idx >> 5, i = idx & 31;
    float off = (float)(*offp);
    float inv = powf(10000.0f, -(float)(2 * i) / 64.0f);
    float ang = ((float)t + off) * inv;
    float s, c;
    sincosf(ang, &s, &c);
    tab[idx * 2]     = c;
    tab[idx * 2 + 1] = s;
}

// ------- 64x64 tile transpose + downconvert: in fp32 [bz][R][C] -> out bf16 [bz][C][R] -------
__global__ void k_transposeF2B(const float* __restrict__ in,
                               unsigned short* __restrict__ out, int R, int C) {
    __shared__ __align__(16) float tile[64 * 68];
    const int bz = blockIdx.z;
    const size_t base = (size_t)bz * R * C;
    const int tR = blockIdx.y * 64, tC = blockIdx.x * 64;
    const int tid = threadIdx.x;
#pragma unroll
    for (int it = 0; it < 4; ++it) {
        int flat = (it * 256 + tid) * 4;
        int r = flat >> 6, c = flat & 63;
        *(float4*)&tile[r * 68 + c] =
            *(const float4*)&in[base + (size_t)(tR + r) * C + tC + c];
    }
    __syncthreads();
#pragma unroll
    for (int it = 0; it < 2; ++it) {
        int flat = (it * 256 + tid) * 8;
        int rr = flat >> 6, cc = flat & 63;
        ushort8_t v;
#pragma unroll
        for (int j = 0; j < 8; ++j) v[j] = f2bf(tile[(cc + j) * 68 + rr]);
        *(ushort8_t*)&out[base + (size_t)(tC + rr) * R + tR + cc] = v;
    }
}

// ---------------- batched bf16 64x64 tile transpose: in[bz][R][C] -> out[bz][C][R] ----------------
__global__ void k_transpose64(const unsigned short* __restrict__ in,
                              unsigned short* __restrict__ out, int R, int C) {
    __shared__ __align__(16) unsigned short tile[64 * 72];
    const int bz = blockIdx.z;
    const size_t base = (size_t)bz * R * C;
    const int tR = blockIdx.y * 64, tC = blockIdx.x * 64;
    const int tid = threadIdx.x;
#pragma unroll
    for (int it = 0; it < 2; ++it) {
        int flat = (it * 256 + tid) * 8;
        int r = flat >> 6, c = flat & 63;
        *(ushort8_t*)&tile[r * 72 + c] =
            *(const ushort8_t*)&in[base + (size_t)(tR + r) * C + tC + c];
    }
    __syncthreads();
#pragma unroll
    for (int it = 0; it < 2; ++it) {
        int flat = (it * 256 + tid) * 8;
        int rr = flat >> 6, cc = flat & 63;
        ushort8_t v;
#pragma unroll
        for (int j = 0; j < 8; ++j) v[j] = tile[(cc + j) * 72 + rr];
        *(ushort8_t*)&out[base + (size_t)(tC + rr) * R + tR + cc] = v;
    }
}

// ================= 256x256 MFMA GEMM, K=1024, BK=64, 8-wave, 8-phase schedule =================
// T1 XCD swizzle; T2 LDS XOR swizzle (linear gload_lds dest, pre-swizzled global src);
// T3/T4 4-slot half-tile ring, A-half of slot s staged at phase 2s+1, B at 2s+2 (mod 8).
//   m201 cadence: vmcnt(6) at phases 0 and 4 ONLY (round-2 change; round-1 had it at all
//   even phases = 2x the forced-wait points). Trace: p0-wait outstanding 16, forces 10
//   oldest = both halves of slots 0,1 (read p0-p3); p4-wait forces slots 2,3 (read p4-p7).
//   Prologue vmcnt(8) forces A0,B0,A01; peeled tail waits 6/0.
// T5 setprio(1) around each 16-MFMA cluster.
template <int EPI>
__global__ __launch_bounds__(512, 2) void k_gemm(
    const unsigned short* __restrict__ A,
    const unsigned short* __restrict__ Bt,
    const float* __restrict__ bias,
    const float* __restrict__ tab,
    unsigned short* __restrict__ oq,
    unsigned short* __restrict__ ok,
    unsigned short* __restrict__ ov,
    float* __restrict__ cache,
    float* __restrict__ outp)
{
    constexpr int K = 1024;
    __shared__ __align__(16) unsigned short lds[65536];   // 128 KiB
    unsigned short* lA = lds;                    // 4 slots x 8192 ushorts (16 KB)
    unsigned short* lB = lds + 32768;

    const int tid  = threadIdx.x;
    const int lane = tid & 63, w = tid >> 6;
    const int wr = w >> 2, wc = w & 3;           // 2 x 4 wave grid
    const int lrow = lane & 15, quad = lane >> 4;

    // --- T1: XCD-aware bijective swizzle (nwg % 8 == 0 for both launches) ---
    const int gx  = gridDim.x;
    const int nwg = gx * gridDim.y;
    const int bid = blockIdx.y * gx + blockIdx.x;
    const int sw  = (bid & 7) * (nwg >> 3) + (bid >> 3);
    const int blockM = (sw / gx) * 256;
    const int blockN = (sw % gx) * 256;

    // --- staging: linear LDS dest, pre-swizzled global source (T2, rule #21) ---
    const int q8    = (lane & 7) ^ (lane >> 3);
    const int srow0 = ((w * 16 + (lane >> 3)) << 1) + ((q8 >> 2) & 1);
    const int scol  = (q8 & 3) * 8;
    const unsigned short* srcA = A  + (size_t)(blockM + srow0) * K + scol;
    const unsigned short* srcB = Bt + (size_t)(blockN + srow0) * K + scol;
    unsigned short* dA = lA + w * 1024;          // + slot*8192 at use
    unsigned short* dB = lB + w * 1024;

    // --- frag reads: same XOR on the read side -> conflict-free b128 ---
    const int rp   = lrow >> 1;
    const int swzu = ((((lane & 1) << 6) | (quad << 4)) ^ (rp << 4)) >> 1;

    f32x4 acc[8][4];
#pragma unroll
    for (int m = 0; m < 8; ++m)
#pragma unroll
        for (int n = 0; n < 4; ++n) acc[m][n] = (f32x4){0.f, 0.f, 0.f, 0.f};

#define STAGE_A(T, KH) do { \
        const unsigned short* s_ = srcA + (T) * 64 + (KH) * 32; \
        unsigned short* d_ = dA + (((2*(T)+(KH)) & 3) << 13); \
        gload_lds16(s_, d_); \
        gload_lds16(s_ + 16 * K, d_ + 512); } while (0)
#define STAGE_B(T, KH) do { \
        const unsigned short* s_ = srcB + (T) * 64 + (KH) * 32; \
        unsigned short* d_ = dB + (((2*(T)+(KH)) & 3) << 13); \
        gload_lds16(s_, d_); \
        gload_lds16(s_ + 16 * K, d_ + 512); } while (0)
#define WAITN(n) asm volatile("s_waitcnt vmcnt(" #n ")" ::: "memory")
#define RD_A(slot) do { \
        _Pragma("unroll") \
        for (int m = 0; m < 8; ++m) \
            aA[m] = ld8(&lA[((slot) << 13) + (wr * 64 + m * 8 + rp) * 64 + swzu]); } while (0)
#define RD_B(slot, nh) do { \
        _Pragma("unroll") \
        for (int nl = 0; nl < 2; ++nl) \
            bB[nl] = ld8(&lB[((slot) << 13) + (wc * 32 + (nh) * 16 + nl * 8 + rp) * 64 + swzu]); } while (0)
#define MFMA16(nh) do { \
        __builtin_amdgcn_s_barrier(); \
        asm volatile("s_waitcnt lgkmcnt(0)" ::: "memory"); \
        __builtin_amdgcn_sched_barrier(0); \
        __builtin_amdgcn_s_setprio(1); \
        _Pragma("unroll") \
        for (int m = 0; m < 8; ++m) { \
            acc[m][(nh)*2+0] = __builtin_amdgcn_mfma_f32_16x16x32_bf16(aA[m], bB[0], acc[m][(nh)*2+0], 0, 0, 0); \
            acc[m][(nh)*2+1] = __builtin_amdgcn_mfma_f32_16x16x32_bf16(aA[m], bB[1], acc[m][(nh)*2+1], 0, 0, 0); } \
        __builtin_amdgcn_s_setprio(0); \
        __builtin_amdgcn_s_barrier(); } while (0)

    // prologue: 7 halves (14 loads), oldest-first = A0,B0,A1,B1,A2,B2,A3
    STAGE_A(0, 0); STAGE_B(0, 0);
    STAGE_A(0, 1); STAGE_B(0, 1);
    STAGE_A(1, 0); STAGE_B(1, 0);
    STAGE_A(1, 1);
    asm volatile("s_waitcnt vmcnt(8)" ::: "memory");   // forces A(0,0),B(0,0),A(0,1)
    __builtin_amdgcn_s_barrier();

    bf16x8 aA[8], bB[2];
    for (int i = 0; i < 7; ++i) {
        const int E = 2 * i, O = 2 * i + 1;
        WAITN(6); RD_A(0); RD_B(0, 0); STAGE_B(O, 1);     MFMA16(0);   // p0
        RD_B(0, 1);                    STAGE_A(E + 2, 0); MFMA16(1);   // p1
        RD_A(1); RD_B(1, 0);           STAGE_B(E + 2, 0); MFMA16(0);   // p2
        RD_B(1, 1);                    STAGE_A(E + 2, 1); MFMA16(1);   // p3
        WAITN(6); RD_A(2); RD_B(2, 0); STAGE_B(E + 2, 1); MFMA16(0);   // p4
        RD_B(2, 1);                    STAGE_A(O + 2, 0); MFMA16(1);   // p5
        RD_A(3); RD_B(3, 0);           STAGE_B(O + 2, 0); MFMA16(0);   // p6
        RD_B(3, 1);                    STAGE_A(O + 2, 1); MFMA16(1);   // p7
    }
    // final iteration (E=14, O=15): only B(15,1) still to stage; waits 6 then 0
    WAITN(6); RD_A(0); RD_B(0, 0); STAGE_B(15, 1); MFMA16(0);
    RD_B(0, 1);                                    MFMA16(1);
    RD_A(1); RD_B(1, 0);                           MFMA16(0);
    RD_B(1, 1);                                    MFMA16(1);
    WAITN(0); RD_A(2); RD_B(2, 0);                 MFMA16(0);
    RD_B(2, 1);                                    MFMA16(1);
    RD_A(3); RD_B(3, 0);                           MFMA16(0);
    RD_B(3, 1);                                    MFMA16(1);
#undef STAGE_A
#undef STAGE_B
#undef WAITN
#undef RD_A
#undef RD_B
#undef MFMA16

    // ---------------- epilogue ----------------
#pragma unroll
    for (int m = 0; m < 8; ++m) {
        const int rbase = blockM + wr * 128 + m * 16 + quad * 4;
#pragma unroll
        for (int n = 0; n < 4; ++n) {
            const int gcol = blockN + wc * 64 + n * 16 + lrow;
            const float bv = bias[gcol];
#pragma unroll
            for (int r = 0; r < 4; ++r) {
                const int row = rbase + r;
                float val = acc[m][n][r] + bv;
                if (EPI == 0) {
                    outp[(size_t)row * 1024 + gcol] = val;
                } else {
                    const int s = gcol >> 10;          // 0:q 1:k 2:v (uniform per block)
                    const int cn = gcol & 1023;
                    const int h = cn >> 6, d = cn & 63;
                    const int b = row >> 11, t = row & 2047;
                    if (s < 2) {  // RoPE; pair element is in the adjacent lane
                        const int ii = d >> 1;
                        const float cz = tab[t * 64 + 2 * ii];
                        const float sz = tab[t * 64 + 2 * ii + 1];
                        const float pv = __shfl_xor(val, 1);
                        val = (d & 1) ? (pv * sz + val * cz) : (val * cz - pv * sz);
                    }
                    const unsigned short r16 = f2bf(val);
                    const size_t bhtd = (((size_t)(b * 16 + h)) * 2048 + t) * 64 + d;
                    if (s == 0) {
                        oq[bhtd] = r16;
                    } else if (s == 1) {
                        ok[bhtd] = r16;
                        cache[(((size_t)(b * 2 + 0)) * 2048 + t) * 1024 + h * 64 + d] = val;
                    } else {
                        ov[bhtd] = r16;
                        cache[(((size_t)(b * 2 + 1)) * 2048 + t) * 1024 + h * 64 + d] = val;
                    }
                }
            }
        }
    }
}

// ---------------- flash attention (causal), merged triangle pair, deep pipeline ----------------
// Round-2 counters: 67 us, MfmaUtil 11%, VALUBusy 19% -> per-tile ~5000 cyc vs ~1400 cyc
// of work: the per-tile __syncthreads() drained vmcnt(0), stalling on loads issued only
// one compute-phase earlier. Fix (T3/T4): 4-slot K/V ring, depth-2 prefetch, raw s_barrier
// + counted vmcnt per iteration:
//   [stage(it+2); vmcnt(4)] / tail: vmcnt(2), vmcnt(0); s_barrier; compute slot it&3.
// RAW: tile it forced by each wave's own vmcnt(4) (oldest pair) before barrier(it).
// WAR: stage(it+2) issues after barrier(it-1); slot's last readers finished compute(it-2)
// before they arrived at barrier(it-1). T5 setprio around MFMA clusters.
__global__ __launch_bounds__(512, 2) void k_attn(
    const unsigned short* __restrict__ qh,   // [B][H][T][64] bf16
    const unsigned short* __restrict__ kh,   // [B][H][T][64] bf16
    const unsigned short* __restrict__ vt,   // [B][H][64][T] bf16
    unsigned short* __restrict__ ctx)        // [B*T][1024]   bf16
{
    __shared__ __align__(16) unsigned short lK[4][64 * 64];
    __shared__ __align__(16) unsigned short lV[4][64 * 64];
    __shared__ __align__(16) unsigned short lP[8][32 * 68];
    const int tid = threadIdx.x;
    const int wave = tid >> 6, lane = tid & 63;
    const int lrow = lane & 15, quad = lane >> 4;
    const int sub = lane >> 3, g8 = lane & 7;
    const int grp = g8 ^ (sub & 7);
    const int pj = blockIdx.x;               // 0..7
    const int h = blockIdx.y, b = blockIdx.z;
    const unsigned short* Q  = qh + (size_t)(b * 16 + h) * 2048 * 64;
    const unsigned short* Kp = kh + (size_t)(b * 16 + h) * 2048 * 64;
    const unsigned short* Vt = vt + (size_t)(b * 16 + h) * 64 * 2048;

    const int grpq = wave >> 2;              // 0: long q-block, 1: short
    const int wv   = wave & 3;
    const int qb   = grpq ? pj : (15 - pj);
    const int qw   = qb * 128 + wv * 32;     // this wave's first q row
    const int nT   = 2 * (16 - pj);          // 64-col K/V tiles staged (covers both groups)

    bf16x8 bOnes;
#pragma unroll
    for (int j = 0; j < 8; ++j) bOnes[j] = (bf16_t)1.0f;

    // Q fragments, pre-scaled by 1/sqrt(64)=0.125 (exact in bf16)
    bf16x8 aQ[2][2];
#pragma unroll
    for (int mf = 0; mf < 2; ++mf)
#pragma unroll
        for (int ks = 0; ks < 2; ++ks) {
            bf16x8 t = ld8(&Q[(size_t)(qw + mf * 16 + lrow) * 64 + ks * 32 + quad * 8]);
#pragma unroll
            for (int j = 0; j < 8; ++j) t[j] = (bf16_t)((float)t[j] * 0.125f);
            aQ[mf][ks] = t;
        }

    f32x4 o[2][4];
#pragma unroll
    for (int mf = 0; mf < 2; ++mf)
#pragma unroll
        for (int i = 0; i < 4; ++i) o[mf][i] = (f32x4){0.f, 0.f, 0.f, 0.f};
    f32x4 lacc[2];
    lacc[0] = (f32x4){0.f, 0.f, 0.f, 0.f};
    lacc[1] = (f32x4){0.f, 0.f, 0.f, 0.f};

    // stage tile t into ring slot t&3 (2 issues/wave: 1 K chunk + 1 V chunk)
#define STAGE_T(t) do { \
        const int c_ = wave, s_ = (t) & 3; \
        gload_lds16(&Kp[(size_t)((t) * 64 + c_ * 8 + sub) * 64 + grp * 8], &lK[s_][c_ * 512]); \
        gload_lds16(&Vt[(size_t)(c_ * 8 + sub) * 2048 + (t) * 64 + grp * 8], &lV[s_][c_ * 512]); } while (0)

    STAGE_T(0);
    STAGE_T(1);

    for (int it = 0; it < nT; ++it) {
        if (it + 2 < nT) {
            STAGE_T(it + 2);
            asm volatile("s_waitcnt vmcnt(4)" ::: "memory");   // forces own tile-it pair
        } else if (it + 1 < nT) {
            asm volatile("s_waitcnt vmcnt(2)" ::: "memory");
        } else {
            asm volatile("s_waitcnt vmcnt(0)" ::: "memory");
        }
        __builtin_amdgcn_s_barrier();
        __builtin_amdgcn_sched_barrier(0);
        const int kt0 = it * 64;
        if (kt0 < qw + 32) {
            const unsigned short* lKb = lK[it & 3];
            const unsigned short* lVb = lV[it & 3];
            f32x4 s[2][4];
#pragma unroll
            for (int mf = 0; mf < 2; ++mf)
#pragma unroll
                for (int i = 0; i < 4; ++i) s[mf][i] = (f32x4){0.f, 0.f, 0.f, 0.f};
            __builtin_amdgcn_s_setprio(1);
#pragma unroll
            for (int nt = 0; nt < 4; ++nt) {
                const int row = nt * 16 + lrow;
#pragma unroll
                for (int ks = 0; ks < 2; ++ks) {
                    bf16x8 bK = ld8(&lKb[row * 64 + (((ks * 4 + quad) ^ (row & 7)) * 8)]);
#pragma unroll
                    for (int mf = 0; mf < 2; ++mf)
                        s[mf][nt] = __builtin_amdgcn_mfma_f32_16x16x32_bf16(
                            aQ[mf][ks], bK, s[mf][nt], 0, 0, 0);
                }
            }
            __builtin_amdgcn_s_setprio(0);
            // p = exp(s); only the diagonal tile needs the causal mask
            if (kt0 + 63 > qw) {
#pragma unroll
                for (int mf = 0; mf < 2; ++mf)
#pragma unroll
                    for (int nt = 0; nt < 4; ++nt) {
                        const int colg = kt0 + nt * 16 + lrow;
#pragma unroll
                        for (int r = 0; r < 4; ++r) {
                            const int rowg = qw + mf * 16 + quad * 4 + r;
                            const float pv = (colg <= rowg) ? __expf(s[mf][nt][r]) : 0.f;
                            lP[wave][(mf * 16 + quad * 4 + r) * 68 + nt * 16 + lrow] = f2bf(pv);
                        }
                    }
            } else {
#pragma unroll
                for (int mf = 0; mf < 2; ++mf)
#pragma unroll
                    for (int nt = 0; nt < 4; ++nt)
#pragma unroll
                        for (int r = 0; r < 4; ++r)
                            lP[wave][(mf * 16 + quad * 4 + r) * 68 + nt * 16 + lrow] =
                                f2bf(__expf(s[mf][nt][r]));
            }
            bf16x8 aP[2][2];
#pragma unroll
            for (int mf = 0; mf < 2; ++mf)
#pragma unroll
                for (int ks = 0; ks < 2; ++ks)
                    aP[mf][ks] = ld8(&lP[wave][(mf * 16 + lrow) * 68 + ks * 32 + quad * 8]);
            __builtin_amdgcn_s_setprio(1);
#pragma unroll
            for (int mf = 0; mf < 2; ++mf)
#pragma unroll
                for (int ks = 0; ks < 2; ++ks)
                    lacc[mf] = __builtin_amdgcn_mfma_f32_16x16x32_bf16(
                        aP[mf][ks], bOnes, lacc[mf], 0, 0, 0);
#pragma unroll
            for (int dt = 0; dt < 4; ++dt) {
                const int row = dt * 16 + lrow;
#pragma unroll
                for (int ks = 0; ks < 2; ++ks) {
                    bf16x8 bV = ld8(&lVb[row * 64 + (((ks * 4 + quad) ^ (row & 7)) * 8)]);
#pragma unroll
                    for (int mf = 0; mf < 2; ++mf)
                        o[mf][dt] = __builtin_amdgcn_mfma_f32_16x16x32_bf16(
                            aP[mf][ks], bV, o[mf][dt], 0, 0, 0);
                }
            }
            __builtin_amdgcn_s_setprio(0);
        }
    }
#undef STAGE_T

    float inv[2][4];
#pragma unroll
    for (int mf = 0; mf < 2; ++mf)
#pragma unroll
        for (int r = 0; r < 4; ++r) inv[mf][r] = 1.0f / lacc[mf][r];
#pragma unroll
    for (int mf = 0; mf < 2; ++mf)
#pragma unroll
        for (int dt = 0; dt < 4; ++dt) {
            const int col = h * 64 + dt * 16 + lrow;
#pragma unroll
            for (int r = 0; r < 4; ++r) {
                const int trow = qw + mf * 16 + quad * 4 + r;
                ctx[((size_t)(b * 2048 + trow)) * 1024 + col] = f2bf(o[mf][dt][r] * inv[mf][r]);
            }
        }
}

extern "C" void kernel_launch(void* const* d_in, const int* in_sizes, int n_in,
                              void* d_out, int out_size, void* d_ws, size_t ws_size,
                              hipStream_t stream) {
    (void)in_sizes; (void)n_in; (void)out_size; (void)ws_size;
    const float* x    = (const float*)d_in[0];
    const float* wqkv = (const float*)d_in[1];
    const float* bqkv = (const float*)d_in[2];
    const float* wout = (const float*)d_in[3];
    const float* bout = (const float*)d_in[4];
    const int*   offp = (const int*)d_in[5];

    float* out   = (float*)d_out;
    float* cache = out + (size_t)2 * 2048 * 1024;   // 4,194,304 fp32 elems

    char* w = (char*)d_ws;
    float* tab            = (float*)w;          w += (size_t)2048 * 64 * sizeof(float);
    unsigned short* xb    = (unsigned short*)w; w += (size_t)4194304 * 2;
    unsigned short* wqkvT = (unsigned short*)w; w += (size_t)3072 * 1024 * 2;
    unsigned short* woutT = (unsigned short*)w; w += (size_t)1024 * 1024 * 2;
    unsigned short* qh    = (unsigned short*)w; w += (size_t)4194304 * 2;
    unsigned short* kh    = (unsigned short*)w; w += (size_t)4194304 * 2;
    unsigned short* vh    = (unsigned short*)w; w += (size_t)4194304 * 2;
    unsigned short* vt    = (unsigned short*)w; w += (size_t)4194304 * 2;
    unsigned short* ctx   = (unsigned short*)w; w += (size_t)4194304 * 2;

    k_ropetab<<<dim3(256), dim3(256), 0, stream>>>(tab, offp);
    // x fp32 [4096][1024] -> xb bf16
    k_cvt<<<dim3(2048), dim3(256), 0, stream>>>(x, xb);
    // Wqkv fp32 [1024][3072] -> WqkvT bf16 [3072][1024]
    k_transposeF2B<<<dim3(48, 16, 1), dim3(256), 0, stream>>>(wqkv, wqkvT, 1024, 3072);
    // Wout fp32 [1024][1024] -> WoutT bf16 [1024][1024]
    k_transposeF2B<<<dim3(16, 16, 1), dim3(256), 0, stream>>>(wout, woutT, 1024, 1024);
    // QKV projection + bias + RoPE + scatter: 256x256 tiles -> grid (3072/256, 4096/256)
    k_gemm<1><<<dim3(12, 16), dim3(512), 0, stream>>>(xb, wqkvT, bqkv, tab, qh, kh, vh, cache, nullptr);
    // V bf16 [bh][2048][64] -> Vt bf16 [bh][64][2048]
    k_transpose64<<<dim3(1, 32, 32), dim3(256), 0, stream>>>(vh, vt, 2048, 64);
    // flash attention -> ctx bf16 (merged triangle pair: 256 blocks x 8 waves, deep pipeline)
    k_attn<<<dim3(8, 16, 2), dim3(512), 0, stream>>>(qh, kh, vt, ctx);
    // out projection -> fp32 out: grid (1024/256, 4096/256)
    k_gemm<0><<<dim3(4, 16), dim3(512), 0, stream>>>(ctx, woutT, bout, tab, nullptr, nullptr, nullptr, nullptr, out);
}

// Round 4
// 249.852 us; speedup vs baseline: 1.0331x; 1.0015x over previous
//
#include <hip/hip_runtime.h>
#include <stdint.h>
#include <math.h>

// Problem: B=2, T=2048, H=16, hd=64, D=1024, 3D=3072
// I/O dtype: float32 (per reference). Internal MFMA pipeline: bf16.
// d_out: [out (2,2048,1024)] ++ [new_cache (2,2,2048,16,64)], fp32
// d_in: x, Wqkv, bqkv, Wout, bout (fp32), offset (int32)

typedef __bf16 bf16_t;
typedef bf16_t bf16x8 __attribute__((ext_vector_type(8)));
typedef float f32x4 __attribute__((ext_vector_type(4)));
typedef unsigned short ushort8_t __attribute__((ext_vector_type(8)));

__device__ __forceinline__ unsigned short f2bf(float f) {
    union { float f; unsigned int i; } v; v.f = f;
    unsigned int r = v.i + 0x7fffu + ((v.i >> 16) & 1u);
    return (unsigned short)(r >> 16);
}
__device__ __forceinline__ bf16x8 ld8(const unsigned short* p) {
    return *(const bf16x8*)p;
}
// Inline-asm LDS read: invisible to SIInsertWaitcnts, so the compiler cannot
// insert a conservative vmcnt drain ordering it against global_load_lds DMA.
// Correctness: OUR counted s_waitcnt vmcnt(N) + s_barrier precede these reads;
// lgkmcnt(0) + sched_barrier(0) precede the consuming MFMAs (rule #18).
__device__ __forceinline__ bf16x8 lds_rd128(const unsigned short* p) {
    bf16x8 r;
    asm volatile("ds_read_b128 %0, %1"
                 : "=v"(r)
                 : "v"((const __attribute__((address_space(3))) unsigned short*)p));
    return r;
}
__device__ __forceinline__ void gload_lds16(const unsigned short* g, unsigned short* l) {
    __builtin_amdgcn_global_load_lds(
        (__attribute__((address_space(1))) void*)(g),
        (__attribute__((address_space(3))) void*)(l),
        16, 0, 0);
}
#define LGK(n) asm volatile("s_waitcnt lgkmcnt(" #n ")" ::: "memory")
#define WAITN(n) asm volatile("s_waitcnt vmcnt(" #n ")" ::: "memory")

// ---------------- fp32 -> bf16 bulk convert (8 elems/thread) ----------------
__global__ void k_cvt(const float* __restrict__ in, unsigned short* __restrict__ out) {
    const int i = (blockIdx.x * 256 + threadIdx.x) * 8;
    float4 a = *(const float4*)&in[i];
    float4 b = *(const float4*)&in[i + 4];
    ushort8_t v;
    v[0] = f2bf(a.x); v[1] = f2bf(a.y); v[2] = f2bf(a.z); v[3] = f2bf(a.w);
    v[4] = f2bf(b.x); v[5] = f2bf(b.y); v[6] = f2bf(b.z); v[7] = f2bf(b.w);
    *(ushort8_t*)&out[i] = v;
}

// ---------------- RoPE cos/sin table: tab[t][i][2], t<2048, i<32 ----------------
__global__ void k_ropetab(float* __restrict__ tab, const int* __restrict__ offp) {
    int idx = blockIdx.x * blockDim.x + threadIdx.x;   // 65536 threads
    int t = idx >> 5, i = idx & 31;
    float off = (float)(*offp);
    float inv = powf(10000.0f, -(float)(2 * i) / 64.0f);
    float ang = ((float)t + off) * inv;
    float s, c;
    sincosf(ang, &s, &c);
    tab[idx * 2]     = c;
    tab[idx * 2 + 1] = s;
}

// ------- 64x64 tile transpose + downconvert: in fp32 [bz][R][C] -> out bf16 [bz][C][R] -------
__global__ void k_transposeF2B(const float* __restrict__ in,
                               unsigned short* __restrict__ out, int R, int C) {
    __shared__ __align__(16) float tile[64 * 68];
    const int bz = blockIdx.z;
    const size_t base = (size_t)bz * R * C;
    const int tR = blockIdx.y * 64, tC = blockIdx.x * 64;
    const int tid = threadIdx.x;
#pragma unroll
    for (int it = 0; it < 4; ++it) {
        int flat = (it * 256 + tid) * 4;
        int r = flat >> 6, c = flat & 63;
        *(float4*)&tile[r * 68 + c] =
            *(const float4*)&in[base + (size_t)(tR + r) * C + tC + c];
    }
    __syncthreads();
#pragma unroll
    for (int it = 0; it < 2; ++it) {
        int flat = (it * 256 + tid) * 8;
        int rr = flat >> 6, cc = flat & 63;
        ushort8_t v;
#pragma unroll
        for (int j = 0; j < 8; ++j) v[j] = f2bf(tile[(cc + j) * 68 + rr]);
        *(ushort8_t*)&out[base + (size_t)(tC + rr) * R + tR + cc] = v;
    }
}

// ---------------- batched bf16 64x64 tile transpose: in[bz][R][C] -> out[bz][C][R] ----------------
__global__ void k_transpose64(const unsigned short* __restrict__ in,
                              unsigned short* __restrict__ out, int R, int C) {
    __shared__ __align__(16) unsigned short tile[64 * 72];
    const int bz = blockIdx.z;
    const size_t base = (size_t)bz * R * C;
    const int tR = blockIdx.y * 64, tC = blockIdx.x * 64;
    const int tid = threadIdx.x;
#pragma unroll
    for (int it = 0; it < 2; ++it) {
        int flat = (it * 256 + tid) * 8;
        int r = flat >> 6, c = flat & 63;
        *(ushort8_t*)&tile[r * 72 + c] =
            *(const ushort8_t*)&in[base + (size_t)(tR + r) * C + tC + c];
    }
    __syncthreads();
#pragma unroll
    for (int it = 0; it < 2; ++it) {
        int flat = (it * 256 + tid) * 8;
        int rr = flat >> 6, cc = flat & 63;
        ushort8_t v;
#pragma unroll
        for (int j = 0; j < 8; ++j) v[j] = tile[(cc + j) * 72 + rr];
        *(ushort8_t*)&out[base + (size_t)(tC + rr) * R + tR + cc] = v;
    }
}

// ================= 256x256 MFMA GEMM, K=1024, BK=64, 8-wave, 8-phase schedule =================
// T1 XCD swizzle; T2 LDS XOR swizzle; T3/T4 4-slot half-tile ring.
// Round-4 changes:
//  (a) fragment reads are inline-asm ds_read_b128 (lds_rd128) -> the compiler's
//      waitcnt pass can no longer insert conservative vmcnt drains ordering them
//      against the global_load_lds DMA (the round-1..3 hidden stall).
//  (b) counted waits moved BEFORE the closing barrier of p3/p7 (wait->barrier->read),
//      so every wave's DMA is forced before ANY wave reads the slot (race-free).
//      Queue trace (steady state, 16 loads/wave/iter): at p3-end 14 outstanding,
//      vmcnt(6) forces slots O(2,3); at p7-end 14, vmcnt(6) forces next-E slots (0,1).
//      Prologue: 14 issued, vmcnt(6) forces slots 0,1. Tail: vmcnt(0) at its p3.
// T5 setprio(1) around each 16-MFMA cluster.
template <int EPI>
__global__ __launch_bounds__(512, 2) void k_gemm(
    const unsigned short* __restrict__ A,
    const unsigned short* __restrict__ Bt,
    const float* __restrict__ bias,
    const float* __restrict__ tab,
    unsigned short* __restrict__ oq,
    unsigned short* __restrict__ ok,
    unsigned short* __restrict__ ov,
    float* __restrict__ cache,
    float* __restrict__ outp)
{
    constexpr int K = 1024;
    __shared__ __align__(16) unsigned short lds[65536];   // 128 KiB
    unsigned short* lA = lds;                    // 4 slots x 8192 ushorts (16 KB)
    unsigned short* lB = lds + 32768;

    const int tid  = threadIdx.x;
    const int lane = tid & 63, w = tid >> 6;
    const int wr = w >> 2, wc = w & 3;           // 2 x 4 wave grid
    const int lrow = lane & 15, quad = lane >> 4;

    // --- T1: XCD-aware bijective swizzle (nwg % 8 == 0 for both launches) ---
    const int gx  = gridDim.x;
    const int nwg = gx * gridDim.y;
    const int bid = blockIdx.y * gx + blockIdx.x;
    const int sw  = (bid & 7) * (nwg >> 3) + (bid >> 3);
    const int blockM = (sw / gx) * 256;
    const int blockN = (sw % gx) * 256;

    // --- staging: linear LDS dest, pre-swizzled global source (T2, rule #21) ---
    const int q8    = (lane & 7) ^ (lane >> 3);
    const int srow0 = ((w * 16 + (lane >> 3)) << 1) + ((q8 >> 2) & 1);
    const int scol  = (q8 & 3) * 8;
    const unsigned short* srcA = A  + (size_t)(blockM + srow0) * K + scol;
    const unsigned short* srcB = Bt + (size_t)(blockN + srow0) * K + scol;
    unsigned short* dA = lA + w * 1024;          // + slot*8192 at use
    unsigned short* dB = lB + w * 1024;

    // --- frag reads: same XOR on the read side -> conflict-free b128 ---
    const int rp   = lrow >> 1;
    const int swzu = ((((lane & 1) << 6) | (quad << 4)) ^ (rp << 4)) >> 1;

    f32x4 acc[8][4];
#pragma unroll
    for (int m = 0; m < 8; ++m)
#pragma unroll
        for (int n = 0; n < 4; ++n) acc[m][n] = (f32x4){0.f, 0.f, 0.f, 0.f};

#define STAGE_A(T, KH) do { \
        const unsigned short* s_ = srcA + (T) * 64 + (KH) * 32; \
        unsigned short* d_ = dA + (((2*(T)+(KH)) & 3) << 13); \
        gload_lds16(s_, d_); \
        gload_lds16(s_ + 16 * K, d_ + 512); } while (0)
#define STAGE_B(T, KH) do { \
        const unsigned short* s_ = srcB + (T) * 64 + (KH) * 32; \
        unsigned short* d_ = dB + (((2*(T)+(KH)) & 3) << 13); \
        gload_lds16(s_, d_); \
        gload_lds16(s_ + 16 * K, d_ + 512); } while (0)
#define RD_A(slot) do { \
        _Pragma("unroll") \
        for (int m = 0; m < 8; ++m) \
            aA[m] = lds_rd128(&lA[((slot) << 13) + (wr * 64 + m * 8 + rp) * 64 + swzu]); } while (0)
#define RD_B(slot, nh) do { \
        _Pragma("unroll") \
        for (int nl = 0; nl < 2; ++nl) \
            bB[nl] = lds_rd128(&lB[((slot) << 13) + (wc * 32 + (nh) * 16 + nl * 8 + rp) * 64 + swzu]); } while (0)
// W: 0 = no wait, 1 = vmcnt(6), 2 = vmcnt(0); placed AFTER the MFMA cluster,
// BEFORE the closing barrier -> the next phases' readers are safe across waves.
#define MFMA16(nh, W) do { \
        __builtin_amdgcn_s_barrier(); \
        asm volatile("s_waitcnt lgkmcnt(0)" ::: "memory"); \
        __builtin_amdgcn_sched_barrier(0); \
        __builtin_amdgcn_s_setprio(1); \
        _Pragma("unroll") \
        for (int m = 0; m < 8; ++m) { \
            acc[m][(nh)*2+0] = __builtin_amdgcn_mfma_f32_16x16x32_bf16(aA[m], bB[0], acc[m][(nh)*2+0], 0, 0, 0); \
            acc[m][(nh)*2+1] = __builtin_amdgcn_mfma_f32_16x16x32_bf16(aA[m], bB[1], acc[m][(nh)*2+1], 0, 0, 0); } \
        __builtin_amdgcn_s_setprio(0); \
        if (W == 1) { WAITN(6); } else if (W == 2) { WAITN(0); } \
        __builtin_amdgcn_s_barrier(); } while (0)

    // prologue: 7 halves (14 loads), oldest-first = A0,B0,A1,B1 then A/B of tile 1
    STAGE_A(0, 0); STAGE_B(0, 0);
    STAGE_A(0, 1); STAGE_B(0, 1);
    STAGE_A(1, 0); STAGE_B(1, 0);
    STAGE_A(1, 1);
    WAITN(6);                      // forces slots 0,1 (A00,B00,A01,B01)
    __builtin_amdgcn_s_barrier();

    bf16x8 aA[8], bB[2];
    for (int i = 0; i < 7; ++i) {
        const int E = 2 * i, O = 2 * i + 1;
        RD_A(0); RD_B(0, 0); STAGE_B(O, 1);     MFMA16(0, 0);   // p0
        RD_B(0, 1);          STAGE_A(E + 2, 0); MFMA16(1, 0);   // p1
        RD_A(1); RD_B(1, 0); STAGE_B(E + 2, 0); MFMA16(0, 0);   // p2
        RD_B(1, 1);          STAGE_A(E + 2, 1); MFMA16(1, 1);   // p3: vmcnt(6) -> slots 2,3
        RD_A(2); RD_B(2, 0); STAGE_B(E + 2, 1); MFMA16(0, 0);   // p4
        RD_B(2, 1);          STAGE_A(O + 2, 0); MFMA16(1, 0);   // p5
        RD_A(3); RD_B(3, 0); STAGE_B(O + 2, 0); MFMA16(0, 0);   // p6
        RD_B(3, 1);          STAGE_A(O + 2, 1); MFMA16(1, 1);   // p7: vmcnt(6) -> next slots 0,1
    }
    // final iteration (E=14, O=15): only B(15,1) still to stage; full drain at its p3
    RD_A(0); RD_B(0, 0); STAGE_B(15, 1); MFMA16(0, 0);
    RD_B(0, 1);                          MFMA16(1, 0);
    RD_A(1); RD_B(1, 0);                 MFMA16(0, 0);
    RD_B(1, 1);                          MFMA16(1, 2);          // vmcnt(0): slots 2,3 + B(15,1)
    RD_A(2); RD_B(2, 0);                 MFMA16(0, 0);
    RD_B(2, 1);                          MFMA16(1, 0);
    RD_A(3); RD_B(3, 0);                 MFMA16(0, 0);
    RD_B(3, 1);                          MFMA16(1, 0);
#undef STAGE_A
#undef STAGE_B
#undef RD_A
#undef RD_B
#undef MFMA16

    // ---------------- epilogue ----------------
#pragma unroll
    for (int m = 0; m < 8; ++m) {
        const int rbase = blockM + wr * 128 + m * 16 + quad * 4;
#pragma unroll
        for (int n = 0; n < 4; ++n) {
            const int gcol = blockN + wc * 64 + n * 16 + lrow;
            const float bv = bias[gcol];
#pragma unroll
            for (int r = 0; r < 4; ++r) {
                const int row = rbase + r;
                float val = acc[m][n][r] + bv;
                if (EPI == 0) {
                    outp[(size_t)row * 1024 + gcol] = val;
                } else {
                    const int s = gcol >> 10;          // 0:q 1:k 2:v (uniform per block)
                    const int cn = gcol & 1023;
                    const int h = cn >> 6, d = cn & 63;
                    const int b = row >> 11, t = row & 2047;
                    if (s < 2) {  // RoPE; pair element is in the adjacent lane
                        const int ii = d >> 1;
                        const float cz = tab[t * 64 + 2 * ii];
                        const float sz = tab[t * 64 + 2 * ii + 1];
                        const float pv = __shfl_xor(val, 1);
                        val = (d & 1) ? (pv * sz + val * cz) : (val * cz - pv * sz);
                    }
                    const unsigned short r16 = f2bf(val);
                    const size_t bhtd = (((size_t)(b * 16 + h)) * 2048 + t) * 64 + d;
                    if (s == 0) {
                        oq[bhtd] = r16;
                    } else if (s == 1) {
                        ok[bhtd] = r16;
                        cache[(((size_t)(b * 2 + 0)) * 2048 + t) * 1024 + h * 64 + d] = val;
                    } else {
                        ov[bhtd] = r16;
                        cache[(((size_t)(b * 2 + 1)) * 2048 + t) * 1024 + h * 64 + d] = val;
                    }
                }
            }
        }
    }
}

// ---------------- flash attention (causal), merged triangle pair, deep pipeline ----------------
// Round-4: all K-loop LDS reads converted to inline-asm ds_read_b128 (same hidden-drain
// fix as the GEMM), with software-pipelined counted lgkmcnt(2)/(0) + sched_barrier(0)
// before each consuming MFMA cluster. lP writes stay plain (same-wave DS ops retire
// in order; lgkmcnt(0) before the aP-consuming MFMAs covers them).
__global__ __launch_bounds__(512, 2) void k_attn(
    const unsigned short* __restrict__ qh,   // [B][H][T][64] bf16
    const unsigned short* __restrict__ kh,   // [B][H][T][64] bf16
    const unsigned short* __restrict__ vt,   // [B][H][64][T] bf16
    unsigned short* __restrict__ ctx)        // [B*T][1024]   bf16
{
    __shared__ __align__(16) unsigned short lK[4][64 * 64];
    __shared__ __align__(16) unsigned short lV[4][64 * 64];
    __shared__ __align__(16) unsigned short lP[8][32 * 68];
    const int tid = threadIdx.x;
    const int wave = tid >> 6, lane = tid & 63;
    const int lrow = lane & 15, quad = lane >> 4;
    const int sub = lane >> 3, g8 = lane & 7;
    const int grp = g8 ^ (sub & 7);
    const int pj = blockIdx.x;               // 0..7
    const int h = blockIdx.y, b = blockIdx.z;
    const unsigned short* Q  = qh + (size_t)(b * 16 + h) * 2048 * 64;
    const unsigned short* Kp = kh + (size_t)(b * 16 + h) * 2048 * 64;
    const unsigned short* Vt = vt + (size_t)(b * 16 + h) * 64 * 2048;

    const int grpq = wave >> 2;              // 0: long q-block, 1: short
    const int wv   = wave & 3;
    const int qb   = grpq ? pj : (15 - pj);
    const int qw   = qb * 128 + wv * 32;     // this wave's first q row
    const int nT   = 2 * (16 - pj);          // 64-col K/V tiles staged (covers both groups)

    bf16x8 bOnes;
#pragma unroll
    for (int j = 0; j < 8; ++j) bOnes[j] = (bf16_t)1.0f;

    // Q fragments, pre-scaled by 1/sqrt(64)=0.125 (exact in bf16)
    bf16x8 aQ[2][2];
#pragma unroll
    for (int mf = 0; mf < 2; ++mf)
#pragma unroll
        for (int ks = 0; ks < 2; ++ks) {
            bf16x8 t = ld8(&Q[(size_t)(qw + mf * 16 + lrow) * 64 + ks * 32 + quad * 8]);
#pragma unroll
            for (int j = 0; j < 8; ++j) t[j] = (bf16_t)((float)t[j] * 0.125f);
            aQ[mf][ks] = t;
        }

    f32x4 o[2][4];
#pragma unroll
    for (int mf = 0; mf < 2; ++mf)
#pragma unroll
        for (int i = 0; i < 4; ++i) o[mf][i] = (f32x4){0.f, 0.f, 0.f, 0.f};
    f32x4 lacc[2];
    lacc[0] = (f32x4){0.f, 0.f, 0.f, 0.f};
    lacc[1] = (f32x4){0.f, 0.f, 0.f, 0.f};

    // stage tile t into ring slot t&3 (2 issues/wave: 1 K chunk + 1 V chunk)
#define STAGE_T(t) do { \
        const int c_ = wave, s_ = (t) & 3; \
        gload_lds16(&Kp[(size_t)((t) * 64 + c_ * 8 + sub) * 64 + grp * 8], &lK[s_][c_ * 512]); \
        gload_lds16(&Vt[(size_t)(c_ * 8 + sub) * 2048 + (t) * 64 + grp * 8], &lV[s_][c_ * 512]); } while (0)

    STAGE_T(0);
    STAGE_T(1);

    for (int it = 0; it < nT; ++it) {
        if (it + 2 < nT) {
            STAGE_T(it + 2);
            WAITN(4);      // forces own tile-it pair; before barrier -> race-free
        } else if (it + 1 < nT) {
            WAITN(2);
        } else {
            WAITN(0);
        }
        __builtin_amdgcn_s_barrier();
        __builtin_amdgcn_sched_barrier(0);
        const int kt0 = it * 64;
        if (kt0 < qw + 32) {
            const unsigned short* lKb = lK[it & 3];
            const unsigned short* lVb = lV[it & 3];
            f32x4 s[2][4];
#pragma unroll
            for (int mf = 0; mf < 2; ++mf)
#pragma unroll
                for (int i = 0; i < 4; ++i) s[mf][i] = (f32x4){0.f, 0.f, 0.f, 0.f};
            // ---- QK^T: asm ds_reads software-pipelined one nt ahead ----
            bf16x8 bK[2][2];
            bK[0][0] = lds_rd128(&lKb[lrow * 64 + ((quad ^ (lrow & 7)) * 8)]);
            bK[0][1] = lds_rd128(&lKb[lrow * 64 + (((4 + quad) ^ (lrow & 7)) * 8)]);
#pragma unroll
            for (int nt = 0; nt < 4; ++nt) {
                const int cur = nt & 1;
                if (nt < 3) {
                    const int row = (nt + 1) * 16 + lrow;
                    bK[cur ^ 1][0] = lds_rd128(&lKb[row * 64 + ((quad ^ (row & 7)) * 8)]);
                    bK[cur ^ 1][1] = lds_rd128(&lKb[row * 64 + (((4 + quad) ^ (row & 7)) * 8)]);
                    LGK(2);
                } else {
                    LGK(0);
                }
                __builtin_amdgcn_sched_barrier(0);
                __builtin_amdgcn_s_setprio(1);
#pragma unroll
                for (int ks = 0; ks < 2; ++ks)
#pragma unroll
                    for (int mf = 0; mf < 2; ++mf)
                        s[mf][nt] = __builtin_amdgcn_mfma_f32_16x16x32_bf16(
                            aQ[mf][ks], bK[cur][ks], s[mf][nt], 0, 0, 0);
                __builtin_amdgcn_s_setprio(0);
            }
            // p = exp(s); only the diagonal tile needs the causal mask
            if (kt0 + 63 > qw) {
#pragma unroll
                for (int mf = 0; mf < 2; ++mf)
#pragma unroll
                    for (int nt = 0; nt < 4; ++nt) {
                        const int colg = kt0 + nt * 16 + lrow;
#pragma unroll
                        for (int r = 0; r < 4; ++r) {
                            const int rowg = qw + mf * 16 + quad * 4 + r;
                            const float pv = (colg <= rowg) ? __expf(s[mf][nt][r]) : 0.f;
                            lP[wave][(mf * 16 + quad * 4 + r) * 68 + nt * 16 + lrow] = f2bf(pv);
                        }
                    }
            } else {
#pragma unroll
                for (int mf = 0; mf < 2; ++mf)
#pragma unroll
                    for (int nt = 0; nt < 4; ++nt)
#pragma unroll
                        for (int r = 0; r < 4; ++r)
                            lP[wave][(mf * 16 + quad * 4 + r) * 68 + nt * 16 + lrow] =
                                f2bf(__expf(s[mf][nt][r]));
            }
            // ---- aP reads (asm), then row-sum MFMAs ----
            bf16x8 aP[2][2];
            aP[0][0] = lds_rd128(&lP[wave][(lrow) * 68 + quad * 8]);
            aP[0][1] = lds_rd128(&lP[wave][(lrow) * 68 + 32 + quad * 8]);
            aP[1][0] = lds_rd128(&lP[wave][(16 + lrow) * 68 + quad * 8]);
            aP[1][1] = lds_rd128(&lP[wave][(16 + lrow) * 68 + 32 + quad * 8]);
            LGK(0);      // also drains the lP writes above (same-wave, in-order DS)
            __builtin_amdgcn_sched_barrier(0);
            __builtin_amdgcn_s_setprio(1);
#pragma unroll
            for (int mf = 0; mf < 2; ++mf)
#pragma unroll
                for (int ks = 0; ks < 2; ++ks)
                    lacc[mf] = __builtin_amdgcn_mfma_f32_16x16x32_bf16(
                        aP[mf][ks], bOnes, lacc[mf], 0, 0, 0);
            __builtin_amdgcn_s_setprio(0);
            // ---- PV: asm ds_reads software-pipelined one dt ahead ----
            bf16x8 bV[2][2];
            bV[0][0] = lds_rd128(&lVb[lrow * 64 + ((quad ^ (lrow & 7)) * 8)]);
            bV[0][1] = lds_rd128(&lVb[lrow * 64 + (((4 + quad) ^ (lrow & 7)) * 8)]);
#pragma unroll
            for (int dt = 0; dt < 4; ++dt) {
                const int cur = dt & 1;
                if (dt < 3) {
                    const int row = (dt + 1) * 16 + lrow;
                    bV[cur ^ 1][0] = lds_rd128(&lVb[row * 64 + ((quad ^ (row & 7)) * 8)]);
                    bV[cur ^ 1][1] = lds_rd128(&lVb[row * 64 + (((4 + quad) ^ (row & 7)) * 8)]);
                    LGK(2);
                } else {
                    LGK(0);
                }
                __builtin_amdgcn_sched_barrier(0);
                __builtin_amdgcn_s_setprio(1);
#pragma unroll
                for (int ks = 0; ks < 2; ++ks)
#pragma unroll
                    for (int mf = 0; mf < 2; ++mf)
                        o[mf][dt] = __builtin_amdgcn_mfma_f32_16x16x32_bf16(
                            aP[mf][ks], bV[cur][ks], o[mf][dt], 0, 0, 0);
                __builtin_amdgcn_s_setprio(0);
            }
        }
    }
#undef STAGE_T

    float inv[2][4];
#pragma unroll
    for (int mf = 0; mf < 2; ++mf)
#pragma unroll
        for (int r = 0; r < 4; ++r) inv[mf][r] = 1.0f / lacc[mf][r];
#pragma unroll
    for (int mf = 0; mf < 2; ++mf)
#pragma unroll
        for (int dt = 0; dt < 4; ++dt) {
            const int col = h * 64 + dt * 16 + lrow;
#pragma unroll
            for (int r = 0; r < 4; ++r) {
                const int trow = qw + mf * 16 + quad * 4 + r;
                ctx[((size_t)(b * 2048 + trow)) * 1024 + col] = f2bf(o[mf][dt][r] * inv[mf][r]);
            }
        }
}

extern "C" void kernel_launch(void* const* d_in, const int* in_sizes, int n_in,
                              void* d_out, int out_size, void* d_ws, size_t ws_size,
                              hipStream_t stream) {
    (void)in_sizes; (void)n_in; (void)out_size; (void)ws_size;
    const float* x    = (const float*)d_in[0];
    const float* wqkv = (const float*)d_in[1];
    const float* bqkv = (const float*)d_in[2];
    const float* wout = (const float*)d_in[3];
    const float* bout = (const float*)d_in[4];
    const int*   offp = (const int*)d_in[5];

    float* out   = (float*)d_out;
    float* cache = out + (size_t)2 * 2048 * 1024;   // 4,194,304 fp32 elems

    char* w = (char*)d_ws;
    float* tab            = (float*)w;          w += (size_t)2048 * 64 * sizeof(float);
    unsigned short* xb    = (unsigned short*)w; w += (size_t)4194304 * 2;
    unsigned short* wqkvT = (unsigned short*)w; w += (size_t)3072 * 1024 * 2;
    unsigned short* woutT = (unsigned short*)w; w += (size_t)1024 * 1024 * 2;
    unsigned short* qh    = (unsigned short*)w; w += (size_t)4194304 * 2;
    unsigned short* kh    = (unsigned short*)w; w += (size_t)4194304 * 2;
    unsigned short* vh    = (unsigned short*)w; w += (size_t)4194304 * 2;
    unsigned short* vt    = (unsigned short*)w; w += (size_t)4194304 * 2;
    unsigned short* ctx   = (unsigned short*)w; w += (size_t)4194304 * 2;

    k_ropetab<<<dim3(256), dim3(256), 0, stream>>>(tab, offp);
    // x fp32 [4096][1024] -> xb bf16
    k_cvt<<<dim3(2048), dim3(256), 0, stream>>>(x, xb);
    // Wqkv fp32 [1024][3072] -> WqkvT bf16 [3072][1024]
    k_transposeF2B<<<dim3(48, 16, 1), dim3(256), 0, stream>>>(wqkv, wqkvT, 1024, 3072);
    // Wout fp32 [1024][1024] -> WoutT bf16 [1024][1024]
    k_transposeF2B<<<dim3(16, 16, 1), dim3(256), 0, stream>>>(wout, woutT, 1024, 1024);
    // QKV projection + bias + RoPE + scatter: 256x256 tiles -> grid (3072/256, 4096/256)
    k_gemm<1><<<dim3(12, 16), dim3(512), 0, stream>>>(xb, wqkvT, bqkv, tab, qh, kh, vh, cache, nullptr);
    // V bf16 [bh][2048][64] -> Vt bf16 [bh][64][2048]
    k_transpose64<<<dim3(1, 32, 32), dim3(256), 0, stream>>>(vh, vt, 2048, 64);
    // flash attention -> ctx bf16 (merged triangle pair: 256 blocks x 8 waves, deep pipeline)
    k_attn<<<dim3(8, 16, 2), dim3(512), 0, stream>>>(qh, kh, vt, ctx);
    // out projection -> fp32 out: grid (1024/256, 4096/256)
    k_gemm<0><<<dim3(4, 16), dim3(512), 0, stream>>>(ctx, woutT, bout, tab, nullptr, nullptr, nullptr, nullptr, out);
}

// Round 5
// 243.093 us; speedup vs baseline: 1.0618x; 1.0278x over previous
//
#include <hip/hip_runtime.h>
#include <stdint.h>
#include <math.h>

// Problem: B=2, T=2048, H=16, hd=64, D=1024, 3D=3072
// I/O dtype: float32 (per reference). Internal MFMA pipeline: bf16.
// d_out: [out (2,2048,1024)] ++ [new_cache (2,2,2048,16,64)], fp32
// d_in: x, Wqkv, bqkv, Wout, bout (fp32), offset (int32)

typedef __bf16 bf16_t;
typedef bf16_t bf16x8 __attribute__((ext_vector_type(8)));
typedef float f32x4 __attribute__((ext_vector_type(4)));
typedef unsigned short ushort8_t __attribute__((ext_vector_type(8)));

__device__ __forceinline__ unsigned short f2bf(float f) {
    union { float f; unsigned int i; } v; v.f = f;
    unsigned int r = v.i + 0x7fffu + ((v.i >> 16) & 1u);
    return (unsigned short)(r >> 16);
}
__device__ __forceinline__ bf16x8 ld8(const unsigned short* p) {
    return *(const bf16x8*)p;
}
__device__ __forceinline__ void gload_lds16(const unsigned short* g, unsigned short* l) {
    __builtin_amdgcn_global_load_lds(
        (__attribute__((address_space(1))) void*)(g),
        (__attribute__((address_space(3))) void*)(l),
        16, 0, 0);
}
#define WAITN(n) asm volatile("s_waitcnt vmcnt(" #n ")" ::: "memory")

// ---------------- fp32 -> bf16 bulk convert (8 elems/thread) ----------------
__global__ void k_cvt(const float* __restrict__ in, unsigned short* __restrict__ out) {
    const int i = (blockIdx.x * 256 + threadIdx.x) * 8;
    float4 a = *(const float4*)&in[i];
    float4 b = *(const float4*)&in[i + 4];
    ushort8_t v;
    v[0] = f2bf(a.x); v[1] = f2bf(a.y); v[2] = f2bf(a.z); v[3] = f2bf(a.w);
    v[4] = f2bf(b.x); v[5] = f2bf(b.y); v[6] = f2bf(b.z); v[7] = f2bf(b.w);
    *(ushort8_t*)&out[i] = v;
}

// ---------------- RoPE cos/sin table: tab[t][i][2], t<2048, i<32 ----------------
__global__ void k_ropetab(float* __restrict__ tab, const int* __restrict__ offp) {
    int idx = blockIdx.x * blockDim.x + threadIdx.x;   // 65536 threads
    int t = idx >> 5, i = idx & 31;
    float off = (float)(*offp);
    float inv = powf(10000.0f, -(float)(2 * i) / 64.0f);
    float ang = ((float)t + off) * inv;
    float s, c;
    sincosf(ang, &s, &c);
    tab[idx * 2]     = c;
    tab[idx * 2 + 1] = s;
}

// ------- 64x64 tile transpose + downconvert: in fp32 [bz][R][C] -> out bf16 [bz][C][R] -------
__global__ void k_transposeF2B(const float* __restrict__ in,
                               unsigned short* __restrict__ out, int R, int C) {
    __shared__ __align__(16) float tile[64 * 68];
    const int bz = blockIdx.z;
    const size_t base = (size_t)bz * R * C;
    const int tR = blockIdx.y * 64, tC = blockIdx.x * 64;
    const int tid = threadIdx.x;
#pragma unroll
    for (int it = 0; it < 4; ++it) {
        int flat = (it * 256 + tid) * 4;
        int r = flat >> 6, c = flat & 63;
        *(float4*)&tile[r * 68 + c] =
            *(const float4*)&in[base + (size_t)(tR + r) * C + tC + c];
    }
    __syncthreads();
#pragma unroll
    for (int it = 0; it < 2; ++it) {
        int flat = (it * 256 + tid) * 8;
        int rr = flat >> 6, cc = flat & 63;
        ushort8_t v;
#pragma unroll
        for (int j = 0; j < 8; ++j) v[j] = f2bf(tile[(cc + j) * 68 + rr]);
        *(ushort8_t*)&out[base + (size_t)(tC + rr) * R + tR + cc] = v;
    }
}

// ---------------- batched bf16 64x64 tile transpose: in[bz][R][C] -> out[bz][C][R] ----------------
__global__ void k_transpose64(const unsigned short* __restrict__ in,
                              unsigned short* __restrict__ out, int R, int C) {
    __shared__ __align__(16) unsigned short tile[64 * 72];
    const int bz = blockIdx.z;
    const size_t base = (size_t)bz * R * C;
    const int tR = blockIdx.y * 64, tC = blockIdx.x * 64;
    const int tid = threadIdx.x;
#pragma unroll
    for (int it = 0; it < 2; ++it) {
        int flat = (it * 256 + tid) * 8;
        int r = flat >> 6, c = flat & 63;
        *(ushort8_t*)&tile[r * 72 + c] =
            *(const ushort8_t*)&in[base + (size_t)(tR + r) * C + tC + c];
    }
    __syncthreads();
#pragma unroll
    for (int it = 0; it < 2; ++it) {
        int flat = (it * 256 + tid) * 8;
        int rr = flat >> 6, cc = flat & 63;
        ushort8_t v;
#pragma unroll
        for (int j = 0; j < 8; ++j) v[j] = tile[(cc + j) * 72 + rr];
        *(ushort8_t*)&out[base + (size_t)(tC + rr) * R + tR + cc] = v;
    }
}

// ================= 256x256 MFMA GEMM, K=1024, BK=64, 8-wave, 8-phase schedule =================
// ROUND-3 VERSION (best measured: 67.4 us for QKV). Round-4's inline-asm ds_read variant
// regressed to 112 us -> reverted; the compiler's own waitcnt handling is the better state.
// T1 XCD swizzle; T2 LDS XOR swizzle; T3/T4 4-slot half-tile ring, vmcnt(6) at p0/p4;
// T5 setprio(1) around each 16-MFMA cluster. Used for the QKV projection (EPI=1) only;
// the out-projection would get just 64 blocks here (75% of chip idle) -> k_gemm0 below.
template <int EPI>
__global__ __launch_bounds__(512, 2) void k_gemm(
    const unsigned short* __restrict__ A,
    const unsigned short* __restrict__ Bt,
    const float* __restrict__ bias,
    const float* __restrict__ tab,
    unsigned short* __restrict__ oq,
    unsigned short* __restrict__ ok,
    unsigned short* __restrict__ ov,
    float* __restrict__ cache,
    float* __restrict__ outp)
{
    constexpr int K = 1024;
    __shared__ __align__(16) unsigned short lds[65536];   // 128 KiB
    unsigned short* lA = lds;                    // 4 slots x 8192 ushorts (16 KB)
    unsigned short* lB = lds + 32768;

    const int tid  = threadIdx.x;
    const int lane = tid & 63, w = tid >> 6;
    const int wr = w >> 2, wc = w & 3;           // 2 x 4 wave grid
    const int lrow = lane & 15, quad = lane >> 4;

    // --- T1: XCD-aware bijective swizzle (nwg % 8 == 0) ---
    const int gx  = gridDim.x;
    const int nwg = gx * gridDim.y;
    const int bid = blockIdx.y * gx + blockIdx.x;
    const int sw  = (bid & 7) * (nwg >> 3) + (bid >> 3);
    const int blockM = (sw / gx) * 256;
    const int blockN = (sw % gx) * 256;

    // --- staging: linear LDS dest, pre-swizzled global source (T2, rule #21) ---
    const int q8    = (lane & 7) ^ (lane >> 3);
    const int srow0 = ((w * 16 + (lane >> 3)) << 1) + ((q8 >> 2) & 1);
    const int scol  = (q8 & 3) * 8;
    const unsigned short* srcA = A  + (size_t)(blockM + srow0) * K + scol;
    const unsigned short* srcB = Bt + (size_t)(blockN + srow0) * K + scol;
    unsigned short* dA = lA + w * 1024;          // + slot*8192 at use
    unsigned short* dB = lB + w * 1024;

    // --- frag reads: same XOR on the read side -> conflict-free b128 ---
    const int rp   = lrow >> 1;
    const int swzu = ((((lane & 1) << 6) | (quad << 4)) ^ (rp << 4)) >> 1;

    f32x4 acc[8][4];
#pragma unroll
    for (int m = 0; m < 8; ++m)
#pragma unroll
        for (int n = 0; n < 4; ++n) acc[m][n] = (f32x4){0.f, 0.f, 0.f, 0.f};

#define STAGE_A(T, KH) do { \
        const unsigned short* s_ = srcA + (T) * 64 + (KH) * 32; \
        unsigned short* d_ = dA + (((2*(T)+(KH)) & 3) << 13); \
        gload_lds16(s_, d_); \
        gload_lds16(s_ + 16 * K, d_ + 512); } while (0)
#define STAGE_B(T, KH) do { \
        const unsigned short* s_ = srcB + (T) * 64 + (KH) * 32; \
        unsigned short* d_ = dB + (((2*(T)+(KH)) & 3) << 13); \
        gload_lds16(s_, d_); \
        gload_lds16(s_ + 16 * K, d_ + 512); } while (0)
#define RD_A(slot) do { \
        _Pragma("unroll") \
        for (int m = 0; m < 8; ++m) \
            aA[m] = ld8(&lA[((slot) << 13) + (wr * 64 + m * 8 + rp) * 64 + swzu]); } while (0)
#define RD_B(slot, nh) do { \
        _Pragma("unroll") \
        for (int nl = 0; nl < 2; ++nl) \
            bB[nl] = ld8(&lB[((slot) << 13) + (wc * 32 + (nh) * 16 + nl * 8 + rp) * 64 + swzu]); } while (0)
#define MFMA16(nh) do { \
        __builtin_amdgcn_s_barrier(); \
        asm volatile("s_waitcnt lgkmcnt(0)" ::: "memory"); \
        __builtin_amdgcn_sched_barrier(0); \
        __builtin_amdgcn_s_setprio(1); \
        _Pragma("unroll") \
        for (int m = 0; m < 8; ++m) { \
            acc[m][(nh)*2+0] = __builtin_amdgcn_mfma_f32_16x16x32_bf16(aA[m], bB[0], acc[m][(nh)*2+0], 0, 0, 0); \
            acc[m][(nh)*2+1] = __builtin_amdgcn_mfma_f32_16x16x32_bf16(aA[m], bB[1], acc[m][(nh)*2+1], 0, 0, 0); } \
        __builtin_amdgcn_s_setprio(0); \
        __builtin_amdgcn_s_barrier(); } while (0)

    // prologue: 7 halves (14 loads), oldest-first = A0,B0,A1,B1 then A/B of tile 1
    STAGE_A(0, 0); STAGE_B(0, 0);
    STAGE_A(0, 1); STAGE_B(0, 1);
    STAGE_A(1, 0); STAGE_B(1, 0);
    STAGE_A(1, 1);
    WAITN(8);                      // forces A(0,0),B(0,0),A(0,1)
    __builtin_amdgcn_s_barrier();

    bf16x8 aA[8], bB[2];
    for (int i = 0; i < 7; ++i) {
        const int E = 2 * i, O = 2 * i + 1;
        WAITN(6); RD_A(0); RD_B(0, 0); STAGE_B(O, 1);     MFMA16(0);   // p0
        RD_B(0, 1);                    STAGE_A(E + 2, 0); MFMA16(1);   // p1
        RD_A(1); RD_B(1, 0);           STAGE_B(E + 2, 0); MFMA16(0);   // p2
        RD_B(1, 1);                    STAGE_A(E + 2, 1); MFMA16(1);   // p3
        WAITN(6); RD_A(2); RD_B(2, 0); STAGE_B(E + 2, 1); MFMA16(0);   // p4
        RD_B(2, 1);                    STAGE_A(O + 2, 0); MFMA16(1);   // p5
        RD_A(3); RD_B(3, 0);           STAGE_B(O + 2, 0); MFMA16(0);   // p6
        RD_B(3, 1);                    STAGE_A(O + 2, 1); MFMA16(1);   // p7
    }
    // final iteration (E=14, O=15): only B(15,1) still to stage; waits 6 then 0
    WAITN(6); RD_A(0); RD_B(0, 0); STAGE_B(15, 1); MFMA16(0);
    RD_B(0, 1);                                    MFMA16(1);
    RD_A(1); RD_B(1, 0);                           MFMA16(0);
    RD_B(1, 1);                                    MFMA16(1);
    WAITN(0); RD_A(2); RD_B(2, 0);                 MFMA16(0);
    RD_B(2, 1);                                    MFMA16(1);
    RD_A(3); RD_B(3, 0);                           MFMA16(0);
    RD_B(3, 1);                                    MFMA16(1);
#undef STAGE_A
#undef STAGE_B
#undef RD_A
#undef RD_B
#undef MFMA16

    // ---------------- epilogue ----------------
#pragma unroll
    for (int m = 0; m < 8; ++m) {
        const int rbase = blockM + wr * 128 + m * 16 + quad * 4;
#pragma unroll
        for (int n = 0; n < 4; ++n) {
            const int gcol = blockN + wc * 64 + n * 16 + lrow;
            const float bv = bias[gcol];
#pragma unroll
            for (int r = 0; r < 4; ++r) {
                const int row = rbase + r;
                float val = acc[m][n][r] + bv;
                if (EPI == 0) {
                    outp[(size_t)row * 1024 + gcol] = val;
                } else {
                    const int s = gcol >> 10;          // 0:q 1:k 2:v (uniform per block)
                    const int cn = gcol & 1023;
                    const int h = cn >> 6, d = cn & 63;
                    const int b = row >> 11, t = row & 2047;
                    if (s < 2) {  // RoPE; pair element is in the adjacent lane
                        const int ii = d >> 1;
                        const float cz = tab[t * 64 + 2 * ii];
                        const float sz = tab[t * 64 + 2 * ii + 1];
                        const float pv = __shfl_xor(val, 1);
                        val = (d & 1) ? (pv * sz + val * cz) : (val * cz - pv * sz);
                    }
                    const unsigned short r16 = f2bf(val);
                    const size_t bhtd = (((size_t)(b * 16 + h)) * 2048 + t) * 64 + d;
                    if (s == 0) {
                        oq[bhtd] = r16;
                    } else if (s == 1) {
                        ok[bhtd] = r16;
                        cache[(((size_t)(b * 2 + 0)) * 2048 + t) * 1024 + h * 64 + d] = val;
                    } else {
                        ov[bhtd] = r16;
                        cache[(((size_t)(b * 2 + 1)) * 2048 + t) * 1024 + h * 64 + d] = val;
                    }
                }
            }
        }
    }
}

// ================= out-projection GEMM: 64x64 tiles, m97-style, 1024 blocks =================
// Round-4 counters: the 256^2 8-phase kernel at grid 64 leaves 75% of the chip idle
// (MfmaUtil 0.47%, 141 us). This op is tiny (8.6 GF): TLP > schedule. 64x64 tile,
// BK=32, double-buffered global_load_lds, grid (16,64)=1024 blocks = 4 blocks/CU
// (16 KB LDS), cross-block TLP covers the staging latency (round-0-verified structure;
// m92 measured 343 TF for 64^2 tiles).
__global__ __launch_bounds__(256) void k_gemm0(
    const unsigned short* __restrict__ A,    // ctx bf16 [4096][1024]
    const unsigned short* __restrict__ Bt,   // woutT bf16 [1024][1024]
    const float* __restrict__ bias,
    float* __restrict__ outp)                // fp32 [4096][1024]
{
    constexpr int K = 1024;
    __shared__ __align__(16) unsigned short lA[2][64 * 32];
    __shared__ __align__(16) unsigned short lB[2][64 * 32];
    const int tid = threadIdx.x;
    const int wave = tid >> 6, lane = tid & 63;
    const int lrow = lane & 15, quad = lane >> 4;
    const int waveM = wave >> 1, waveN = wave & 1;
    const int blockM = blockIdx.y * 64, blockN = blockIdx.x * 64;

    f32x4 acc[2][2];
#pragma unroll
    for (int i = 0; i < 2; ++i)
#pragma unroll
        for (int j = 0; j < 2; ++j) acc[i][j] = (f32x4){0.f, 0.f, 0.f, 0.f};

    const int srow = tid >> 2;           // (tid*8)>>5
    const int scol = (tid & 3) * 8;
    auto stage = [&](int k0, int bsel) {
        gload_lds16(&A[(size_t)(blockM + srow) * K + k0 + scol], &lA[bsel][tid * 8]);
        gload_lds16(&Bt[(size_t)(blockN + srow) * K + k0 + scol], &lB[bsel][tid * 8]);
    };

    stage(0, 0);
    int buf = 0;
    for (int k0 = 0; k0 < K; k0 += 32) {
        __syncthreads();   // staged buf visible; prev compute on buf^1 done
        if (k0 + 32 < K) stage(k0 + 32, buf ^ 1);
        bf16x8 af[2], bfr[2];
#pragma unroll
        for (int mt = 0; mt < 2; ++mt)
            af[mt] = ld8(&lA[buf][(waveM * 32 + mt * 16 + lrow) * 32 + quad * 8]);
#pragma unroll
        for (int nt = 0; nt < 2; ++nt)
            bfr[nt] = ld8(&lB[buf][(waveN * 32 + nt * 16 + lrow) * 32 + quad * 8]);
#pragma unroll
        for (int mt = 0; mt < 2; ++mt)
#pragma unroll
            for (int nt = 0; nt < 2; ++nt)
                acc[mt][nt] = __builtin_amdgcn_mfma_f32_16x16x32_bf16(
                    af[mt], bfr[nt], acc[mt][nt], 0, 0, 0);
        buf ^= 1;
    }

#pragma unroll
    for (int mt = 0; mt < 2; ++mt) {
        const int rbase = blockM + waveM * 32 + mt * 16 + quad * 4;
#pragma unroll
        for (int nt = 0; nt < 2; ++nt) {
            const int gcol = blockN + waveN * 32 + nt * 16 + lrow;
            const float bv = bias[gcol];
#pragma unroll
            for (int r = 0; r < 4; ++r)
                outp[(size_t)(rbase + r) * 1024 + gcol] = acc[mt][nt][r] + bv;
        }
    }
}

// ---------------- flash attention (causal), merged triangle pair, deep pipeline ----------------
// ROUND-3 VERSION (plain LDS loads; round-4's asm-read variant reverted with the GEMM).
// 4-slot K/V ring, depth-2 prefetch, raw s_barrier + counted vmcnt per iteration.
__global__ __launch_bounds__(512, 2) void k_attn(
    const unsigned short* __restrict__ qh,   // [B][H][T][64] bf16
    const unsigned short* __restrict__ kh,   // [B][H][T][64] bf16
    const unsigned short* __restrict__ vt,   // [B][H][64][T] bf16
    unsigned short* __restrict__ ctx)        // [B*T][1024]   bf16
{
    __shared__ __align__(16) unsigned short lK[4][64 * 64];
    __shared__ __align__(16) unsigned short lV[4][64 * 64];
    __shared__ __align__(16) unsigned short lP[8][32 * 68];
    const int tid = threadIdx.x;
    const int wave = tid >> 6, lane = tid & 63;
    const int lrow = lane & 15, quad = lane >> 4;
    const int sub = lane >> 3, g8 = lane & 7;
    const int grp = g8 ^ (sub & 7);
    const int pj = blockIdx.x;               // 0..7
    const int h = blockIdx.y, b = blockIdx.z;
    const unsigned short* Q  = qh + (size_t)(b * 16 + h) * 2048 * 64;
    const unsigned short* Kp = kh + (size_t)(b * 16 + h) * 2048 * 64;
    const unsigned short* Vt = vt + (size_t)(b * 16 + h) * 64 * 2048;

    const int grpq = wave >> 2;              // 0: long q-block, 1: short
    const int wv   = wave & 3;
    const int qb   = grpq ? pj : (15 - pj);
    const int qw   = qb * 128 + wv * 32;     // this wave's first q row
    const int nT   = 2 * (16 - pj);          // 64-col K/V tiles staged (covers both groups)

    bf16x8 bOnes;
#pragma unroll
    for (int j = 0; j < 8; ++j) bOnes[j] = (bf16_t)1.0f;

    // Q fragments, pre-scaled by 1/sqrt(64)=0.125 (exact in bf16)
    bf16x8 aQ[2][2];
#pragma unroll
    for (int mf = 0; mf < 2; ++mf)
#pragma unroll
        for (int ks = 0; ks < 2; ++ks) {
            bf16x8 t = ld8(&Q[(size_t)(qw + mf * 16 + lrow) * 64 + ks * 32 + quad * 8]);
#pragma unroll
            for (int j = 0; j < 8; ++j) t[j] = (bf16_t)((float)t[j] * 0.125f);
            aQ[mf][ks] = t;
        }

    f32x4 o[2][4];
#pragma unroll
    for (int mf = 0; mf < 2; ++mf)
#pragma unroll
        for (int i = 0; i < 4; ++i) o[mf][i] = (f32x4){0.f, 0.f, 0.f, 0.f};
    f32x4 lacc[2];
    lacc[0] = (f32x4){0.f, 0.f, 0.f, 0.f};
    lacc[1] = (f32x4){0.f, 0.f, 0.f, 0.f};

    // stage tile t into ring slot t&3 (2 issues/wave: 1 K chunk + 1 V chunk)
#define STAGE_T(t) do { \
        const int c_ = wave, s_ = (t) & 3; \
        gload_lds16(&Kp[(size_t)((t) * 64 + c_ * 8 + sub) * 64 + grp * 8], &lK[s_][c_ * 512]); \
        gload_lds16(&Vt[(size_t)(c_ * 8 + sub) * 2048 + (t) * 64 + grp * 8], &lV[s_][c_ * 512]); } while (0)

    STAGE_T(0);
    STAGE_T(1);

    for (int it = 0; it < nT; ++it) {
        if (it + 2 < nT) {
            STAGE_T(it + 2);
            WAITN(4);      // forces own tile-it pair; before barrier -> race-free
        } else if (it + 1 < nT) {
            WAITN(2);
        } else {
            WAITN(0);
        }
        __builtin_amdgcn_s_barrier();
        __builtin_amdgcn_sched_barrier(0);
        const int kt0 = it * 64;
        if (kt0 < qw + 32) {
            const unsigned short* lKb = lK[it & 3];
            const unsigned short* lVb = lV[it & 3];
            f32x4 s[2][4];
#pragma unroll
            for (int mf = 0; mf < 2; ++mf)
#pragma unroll
                for (int i = 0; i < 4; ++i) s[mf][i] = (f32x4){0.f, 0.f, 0.f, 0.f};
            __builtin_amdgcn_s_setprio(1);
#pragma unroll
            for (int nt = 0; nt < 4; ++nt) {
                const int row = nt * 16 + lrow;
#pragma unroll
                for (int ks = 0; ks < 2; ++ks) {
                    bf16x8 bK = ld8(&lKb[row * 64 + (((ks * 4 + quad) ^ (row & 7)) * 8)]);
#pragma unroll
                    for (int mf = 0; mf < 2; ++mf)
                        s[mf][nt] = __builtin_amdgcn_mfma_f32_16x16x32_bf16(
                            aQ[mf][ks], bK, s[mf][nt], 0, 0, 0);
                }
            }
            __builtin_amdgcn_s_setprio(0);
            // p = exp(s); only the diagonal tile needs the causal mask
            if (kt0 + 63 > qw) {
#pragma unroll
                for (int mf = 0; mf < 2; ++mf)
#pragma unroll
                    for (int nt = 0; nt < 4; ++nt) {
                        const int colg = kt0 + nt * 16 + lrow;
#pragma unroll
                        for (int r = 0; r < 4; ++r) {
                            const int rowg = qw + mf * 16 + quad * 4 + r;
                            const float pv = (colg <= rowg) ? __expf(s[mf][nt][r]) : 0.f;
                            lP[wave][(mf * 16 + quad * 4 + r) * 68 + nt * 16 + lrow] = f2bf(pv);
                        }
                    }
            } else {
#pragma unroll
                for (int mf = 0; mf < 2; ++mf)
#pragma unroll
                    for (int nt = 0; nt < 4; ++nt)
#pragma unroll
                        for (int r = 0; r < 4; ++r)
                            lP[wave][(mf * 16 + quad * 4 + r) * 68 + nt * 16 + lrow] =
                                f2bf(__expf(s[mf][nt][r]));
            }
            bf16x8 aP[2][2];
#pragma unroll
            for (int mf = 0; mf < 2; ++mf)
#pragma unroll
                for (int ks = 0; ks < 2; ++ks)
                    aP[mf][ks] = ld8(&lP[wave][(mf * 16 + lrow) * 68 + ks * 32 + quad * 8]);
            __builtin_amdgcn_s_setprio(1);
#pragma unroll
            for (int mf = 0; mf < 2; ++mf)
#pragma unroll
                for (int ks = 0; ks < 2; ++ks)
                    lacc[mf] = __builtin_amdgcn_mfma_f32_16x16x32_bf16(
                        aP[mf][ks], bOnes, lacc[mf], 0, 0, 0);
#pragma unroll
            for (int dt = 0; dt < 4; ++dt) {
                const int row = dt * 16 + lrow;
#pragma unroll
                for (int ks = 0; ks < 2; ++ks) {
                    bf16x8 bV = ld8(&lVb[row * 64 + (((ks * 4 + quad) ^ (row & 7)) * 8)]);
#pragma unroll
                    for (int mf = 0; mf < 2; ++mf)
                        o[mf][dt] = __builtin_amdgcn_mfma_f32_16x16x32_bf16(
                            aP[mf][ks], bV, o[mf][dt], 0, 0, 0);
                }
            }
            __builtin_amdgcn_s_setprio(0);
        }
    }
#undef STAGE_T

    float inv[2][4];
#pragma unroll
    for (int mf = 0; mf < 2; ++mf)
#pragma unroll
        for (int r = 0; r < 4; ++r) inv[mf][r] = 1.0f / lacc[mf][r];
#pragma unroll
    for (int mf = 0; mf < 2; ++mf)
#pragma unroll
        for (int dt = 0; dt < 4; ++dt) {
            const int col = h * 64 + dt * 16 + lrow;
#pragma unroll
            for (int r = 0; r < 4; ++r) {
                const int trow = qw + mf * 16 + quad * 4 + r;
                ctx[((size_t)(b * 2048 + trow)) * 1024 + col] = f2bf(o[mf][dt][r] * inv[mf][r]);
            }
        }
}

extern "C" void kernel_launch(void* const* d_in, const int* in_sizes, int n_in,
                              void* d_out, int out_size, void* d_ws, size_t ws_size,
                              hipStream_t stream) {
    (void)in_sizes; (void)n_in; (void)out_size; (void)ws_size;
    const float* x    = (const float*)d_in[0];
    const float* wqkv = (const float*)d_in[1];
    const float* bqkv = (const float*)d_in[2];
    const float* wout = (const float*)d_in[3];
    const float* bout = (const float*)d_in[4];
    const int*   offp = (const int*)d_in[5];

    float* out   = (float*)d_out;
    float* cache = out + (size_t)2 * 2048 * 1024;   // 4,194,304 fp32 elems

    char* w = (char*)d_ws;
    float* tab            = (float*)w;          w += (size_t)2048 * 64 * sizeof(float);
    unsigned short* xb    = (unsigned short*)w; w += (size_t)4194304 * 2;
    unsigned short* wqkvT = (unsigned short*)w; w += (size_t)3072 * 1024 * 2;
    unsigned short* woutT = (unsigned short*)w; w += (size_t)1024 * 1024 * 2;
    unsigned short* qh    = (unsigned short*)w; w += (size_t)4194304 * 2;
    unsigned short* kh    = (unsigned short*)w; w += (size_t)4194304 * 2;
    unsigned short* vh    = (unsigned short*)w; w += (size_t)4194304 * 2;
    unsigned short* vt    = (unsigned short*)w; w += (size_t)4194304 * 2;
    unsigned short* ctx   = (unsigned short*)w; w += (size_t)4194304 * 2;

    k_ropetab<<<dim3(256), dim3(256), 0, stream>>>(tab, offp);
    // x fp32 [4096][1024] -> xb bf16
    k_cvt<<<dim3(2048), dim3(256), 0, stream>>>(x, xb);
    // Wqkv fp32 [1024][3072] -> WqkvT bf16 [3072][1024]
    k_transposeF2B<<<dim3(48, 16, 1), dim3(256), 0, stream>>>(wqkv, wqkvT, 1024, 3072);
    // Wout fp32 [1024][1024] -> WoutT bf16 [1024][1024]
    k_transposeF2B<<<dim3(16, 16, 1), dim3(256), 0, stream>>>(wout, woutT, 1024, 1024);
    // QKV projection + bias + RoPE + scatter: 256x256 tiles -> grid (3072/256, 4096/256)
    k_gemm<1><<<dim3(12, 16), dim3(512), 0, stream>>>(xb, wqkvT, bqkv, tab, qh, kh, vh, cache, nullptr);
    // V bf16 [bh][2048][64] -> Vt bf16 [bh][64][2048]
    k_transpose64<<<dim3(1, 32, 32), dim3(256), 0, stream>>>(vh, vt, 2048, 64);
    // flash attention -> ctx bf16 (merged triangle pair: 256 blocks x 8 waves, deep pipeline)
    k_attn<<<dim3(8, 16, 2), dim3(512), 0, stream>>>(qh, kh, vt, ctx);
    // out projection -> fp32 out: 64x64 tiles, grid (1024/64, 4096/64) = 1024 blocks
    k_gemm0<<<dim3(16, 64), dim3(256), 0, stream>>>(ctx, woutT, bout, out);
}